// Round 13
// baseline (4041.491 us; speedup 1.0000x reference)
//
#include <hip/hip_runtime.h>
#include <hip/hip_bf16.h>
#include <math.h>

// Problem constants
#define HH 180
#define WW 360
#define CC 768
#define FF 91          // kept W-frequencies (km = 91)
#define NPOS (HH*FF)   // 16380 frequency positions
#define NROW (HH*WW)   // 64800 spatial rows
#define LAT 3072

typedef __attribute__((ext_vector_type(8))) short bf16x8;
typedef __attribute__((ext_vector_type(4))) float f32x4;
typedef __attribute__((ext_vector_type(4))) unsigned int u32x4;

__device__ __forceinline__ float gelu_f(float x) {
    return 0.5f * x * (1.0f + erff(x * 0.7071067811865476f));
}

// ---------------- modulation stage A ----------------
__global__ __launch_bounds__(256) void mod_a_kernel(
        const float* __restrict__ e,
        const float* __restrict__ fs_w0, const float* __restrict__ fs_b0,
        const float* __restrict__ ms_w0, const float* __restrict__ ms_b0,
        float* __restrict__ mid_f, float* __restrict__ mid_m) {
    __shared__ float es[64];
    int t = threadIdx.x;
    if (t < 64) es[t] = e[t];
    __syncthreads();
    int j = blockIdx.x * 256 + t;
    if (j < 1536) {
        float a = fs_b0[j];
        #pragma unroll 8
        for (int k = 0; k < 64; k++) a += es[k] * fs_w0[k*1536 + j];
        mid_f[j] = gelu_f(a);
    } else {
        int jm = j - 1536;
        float a = ms_b0[jm];
        #pragma unroll 8
        for (int k = 0; k < 64; k++) a += es[k] * ms_w0[k*6144 + jm];
        mid_m[jm] = gelu_f(a);
    }
}

// ---------------- modulation stage B ----------------
__global__ __launch_bounds__(512) void mod_b_kernel(
        const float* __restrict__ mid_f, const float* __restrict__ mid_m,
        const float* __restrict__ fs_w1, const float* __restrict__ fs_b1,
        const float* __restrict__ ms_w1, const float* __restrict__ ms_b1,
        float* __restrict__ s_f, float* __restrict__ t_f,
        float* __restrict__ s_m, float* __restrict__ t_m) {
    __shared__ float red[8*64];
    int t = threadIdx.x;
    int g = t >> 6;
    int jl = t & 63;
    int blk = blockIdx.x;
    if (blk < 24) {
        int jo = blk*64 + jl;
        const int N = 1536, NQ = 192;
        float a = 0.f;
        const float* w = fs_w1 + (size_t)(g*NQ)*N + jo;
        for (int j = 0; j < NQ; j++) a += mid_f[g*NQ + j] * w[(size_t)j*N];
        red[t] = a;
        __syncthreads();
        if (t < 64) {
            float s = fs_b1[jo];
            #pragma unroll
            for (int q = 0; q < 8; q++) s += red[q*64 + jl];
            if (jo < 768) s_f[jo] = 1.0f + s;
            else          t_f[jo - 768] = s;
        }
    } else {
        int jo = (blk - 24)*64 + jl;
        const int N = 6144, NQ = 768;
        float a = 0.f;
        const float* w = ms_w1 + (size_t)(g*NQ)*N + jo;
        for (int j = 0; j < NQ; j++) a += mid_m[g*NQ + j] * w[(size_t)j*N];
        red[t] = a;
        __syncthreads();
        if (t < 64) {
            float s = ms_b1[jo];
            #pragma unroll
            for (int q = 0; q < 8; q++) s += red[q*64 + jl];
            if (jo < 3072) s_m[jo] = 1.0f + s;
            else           t_m[jo - 3072] = s;
        }
    }
}

// ---------------- LayerNorm bf16 out ----------------
__global__ __launch_bounds__(256) void ln_bf16_kernel(const float* __restrict__ in,
        const float* __restrict__ w, const float* __restrict__ b,
        __hip_bfloat16* __restrict__ out) {
    int row = blockIdx.x*4 + (threadIdx.x >> 6);
    int l = threadIdx.x & 63;
    const float* p = in + (size_t)row*CC;
    float v[12]; float s = 0.f, sq = 0.f;
    #pragma unroll
    for (int i = 0; i < 12; i++) { float tv = p[l + 64*i]; v[i] = tv; s += tv; sq += tv*tv; }
    #pragma unroll
    for (int m = 1; m < 64; m <<= 1) { s += __shfl_xor(s, m); sq += __shfl_xor(sq, m); }
    float mean = s * (1.0f/768.0f);
    float var  = sq * (1.0f/768.0f) - mean*mean;
    float rstd = rsqrtf(var + 1e-5f);
    __hip_bfloat16* o = out + (size_t)row*CC;
    #pragma unroll
    for (int i = 0; i < 12; i++) { int c = l + 64*i; o[c] = __float2bfloat16((v[i]-mean)*rstd*w[c] + b[c]); }
}

// ---------------- twiddle matrices ----------------
__global__ __launch_bounds__(256) void ew_kernel(__hip_bfloat16* __restrict__ Ew) {
    int idx = blockIdx.x*256 + threadIdx.x;
    if (idx >= 192*384) return;
    int r = idx / 384, w = idx - (idx/384)*384;
    int f = (r < 96) ? r : r - 96;
    const float rn = 0.05270462766947299f;  // 1/sqrt(360)
    float v = 0.f;
    if (f < FF && w < WW) {
        int p = (f * w) % 360;
        float ang = 6.283185307179586f/360.0f * (float)p;
        float s_, c_; sincosf(ang, &s_, &c_);
        v = (r < 96) ? c_*rn : -s_*rn;
    }
    Ew[idx] = __float2bfloat16(v);
}

__global__ __launch_bounds__(256) void eh_kernel(__hip_bfloat16* __restrict__ Eh) {
    int idx = blockIdx.x*256 + threadIdx.x;
    if (idx >= 4*192*384) return;
    int sp = idx / (192*384);
    int rem = idx - sp*(192*384);
    int t = rem / 384, k = rem - (rem/384)*384;
    int sig = sp >> 1, plane = sp & 1;
    float s = (sig == 0) ? -1.f : 1.f;
    int h = (k < 192) ? k : k - 192;
    const float rnh = 0.07453559924999299f;  // 1/sqrt(180)
    float v = 0.f;
    if (t < HH && h < HH) {
        int p = (t * h) % 180;
        float ang = 6.283185307179586f/180.0f * (float)p;
        float s_, c_; sincosf(ang, &s_, &c_);
        float C = c_*rnh, S = s_*rnh;
        if (plane == 0) v = (k < 192) ? C : -s*S;
        else            v = (k < 192) ? s*S : C;
    }
    Eh[idx] = __float2bfloat16(v);
}

// ---------------- bd stacked-complex weight pack ----------------
__global__ __launch_bounds__(256) void bdw_kernel(const float* __restrict__ w,
        __hip_bfloat16* __restrict__ Bt) {
    int idx = blockIdx.x*256 + threadIdx.x;   // 8*192*192 = 294912
    if (idx >= 8*192*192) return;
    int wb = idx / (192*192);
    int rem = idx - wb*(192*192);
    int n2 = rem / 192, k2 = rem - (rem/192)*192;
    int k = (k2 < 96) ? k2 : k2 - 96;
    int oc = (n2 < 96) ? n2 : n2 - 96;
    float w0 = w[((size_t)wb*96 + k)*96 + oc];
    float w1v = w[((size_t)(8 + wb)*96 + k)*96 + oc];
    float v;
    if (n2 < 96) v = (k2 < 96) ? w0 : -w1v;
    else         v = (k2 < 96) ? w1v : w0;
    Bt[idx] = __float2bfloat16(v);
}

// ---------------- MFMA transform: C[192 rows][128 c] = A[192][384] @ B[384][c], all bf16 I/O ----------------
template<int MODE>
__global__ __launch_bounds__(256) void transform_mfma(
        const __hip_bfloat16* __restrict__ Amat,
        const __hip_bfloat16* __restrict__ B0, const __hip_bfloat16* __restrict__ B1,
        __hip_bfloat16* __restrict__ O0, __hip_bfloat16* __restrict__ O1) {
    __shared__ __align__(16) unsigned short As[192*72];
    __shared__ __align__(16) unsigned short Bs[128*72];
    int nbase = blockIdx.x * 128;
    int bat = blockIdx.z;
    int tid = threadIdx.x;
    int l = tid & 63, wv = tid >> 6;
    int wm = wv & 1, wn = wv >> 1;
    int lm = l & 15, kq = l >> 4;
    const __hip_bfloat16* Ab = Amat + (MODE == 1 ? (size_t)blockIdx.y*192*384 : 0);
    f32x4 acc[6][4] = {};
    for (int kt = 0; kt < 6; kt++) {
        int kb = kt*64;
        __syncthreads();
        #pragma unroll
        for (int it = 0; it < 6; it++) {
            int ch = it*256 + tid;
            int row = ch >> 3, co = (ch & 7) * 8;
            u32x4 v = *(const u32x4*)(Ab + (size_t)row*384 + kb + co);
            *(u32x4*)(As + row*72 + co) = v;
        }
        #pragma unroll
        for (int it = 0; it < 4; it++) {
            int idx = it*256 + tid;
            int row = idx >> 4;
            int cq = (idx & 15) * 8;
            int k = kb + row;
            unsigned int u[4] = {0u, 0u, 0u, 0u};
            if (MODE == 0) {
                if (k < WW) {
                    u32x4 v = *(const u32x4*)(B0 + (size_t)bat*WW*CC + (size_t)k*CC + nbase + cq);
                    u[0] = v[0]; u[1] = v[1]; u[2] = v[2]; u[3] = v[3];
                }
            } else {
                if (k < 192) {
                    if (k < HH) {
                        u32x4 v = *(const u32x4*)(B0 + (size_t)k*FF*CC + (size_t)bat*CC + nbase + cq);
                        u[0] = v[0]; u[1] = v[1]; u[2] = v[2]; u[3] = v[3];
                    }
                } else {
                    int h2 = k - 192;
                    if (h2 < HH) {
                        u32x4 v = *(const u32x4*)(B1 + (size_t)h2*FF*CC + (size_t)bat*CC + nbase + cq);
                        u[0] = v[0]; u[1] = v[1]; u[2] = v[2]; u[3] = v[3];
                    }
                }
            }
            #pragma unroll
            for (int j = 0; j < 4; j++) {
                Bs[(cq + 2*j    )*72 + row] = (unsigned short)(u[j] & 0xffffu);
                Bs[(cq + 2*j + 1)*72 + row] = (unsigned short)(u[j] >> 16);
            }
        }
        __syncthreads();
        #pragma unroll
        for (int kk = 0; kk < 2; kk++) {
            int kg = kk*32 + kq*8;
            bf16x8 af[6], bfv[4];
            #pragma unroll
            for (int i = 0; i < 6; i++)
                af[i] = *(const bf16x8*)(As + (wm*96 + i*16 + lm)*72 + kg);
            #pragma unroll
            for (int j = 0; j < 4; j++)
                bfv[j] = *(const bf16x8*)(Bs + (wn*64 + j*16 + lm)*72 + kg);
            #pragma unroll
            for (int i = 0; i < 6; i++)
                #pragma unroll
                for (int j = 0; j < 4; j++)
                    acc[i][j] = __builtin_amdgcn_mfma_f32_16x16x32_bf16(af[i], bfv[j], acc[i][j], 0, 0, 0);
        }
    }
    int r0 = kq * 4;
    #pragma unroll
    for (int j = 0; j < 4; j++) {
        int col = nbase + wn*64 + j*16 + lm;
        #pragma unroll
        for (int i = 0; i < 6; i++) {
            #pragma unroll
            for (int r = 0; r < 4; r++) {
                int row = wm*96 + i*16 + r0 + r;
                __hip_bfloat16 hv = __float2bfloat16(acc[i][j][r]);
                if (MODE == 0) {
                    if (row < 96) {
                        if (row < FF) O0[(size_t)bat*FF*CC + (size_t)row*CC + col] = hv;
                    } else {
                        int f2 = row - 96;
                        if (f2 < FF) O1[(size_t)bat*FF*CC + (size_t)f2*CC + col] = hv;
                    }
                } else {
                    if (row < HH) {
                        __hip_bfloat16* Op = blockIdx.y ? O1 : O0;
                        Op[(size_t)row*FF*CC + (size_t)bat*CC + col] = hv;
                    }
                }
            }
        }
    }
}

// ---------------- block-diagonal complex matmul via MFMA (stacked-complex GEMM), bf16 I/O ----------------
template<int LAYER>
__global__ __launch_bounds__(384) void bd_mfma_kernel(
        const __hip_bfloat16* __restrict__ Ir, const __hip_bfloat16* __restrict__ Ii,
        const __hip_bfloat16* __restrict__ Bt,
        const float* __restrict__ bias,
        const float* __restrict__ sf, const float* __restrict__ tf,
        __hip_bfloat16* __restrict__ Or_, __hip_bfloat16* __restrict__ Oi_) {
    __shared__ __align__(16) unsigned short As[128*72];
    __shared__ __align__(16) unsigned short Bs[192*72];
    int mbase = blockIdx.x * 128;
    int wb = blockIdx.y;
    int tid = threadIdx.x;
    int l = tid & 63, wv = tid >> 6;      // 6 waves
    int wm = wv & 1, wn = wv >> 1;
    int lm = l & 15, kq = l >> 4;
    const __hip_bfloat16* Bw = Bt + (size_t)wb*192*192;
    f32x4 acc[4][4] = {};
    for (int kt = 0; kt < 3; kt++) {
        __syncthreads();
        for (int ch = tid; ch < 1024; ch += 384) {
            int row = ch >> 3, q = ch & 7;
            int k2 = kt*64 + q*8;
            int p = mbase + row; if (p >= NPOS) p = NPOS - 1;
            const __hip_bfloat16* src = (k2 < 96) ? (Ir + (size_t)p*CC + wb*96 + k2)
                                                  : (Ii + (size_t)p*CC + wb*96 + (k2 - 96));
            *(u32x4*)(As + row*72 + q*8) = *(const u32x4*)src;
        }
        for (int ch = tid; ch < 1536; ch += 384) {
            int row = ch >> 3, co = (ch & 7) * 8;
            u32x4 v = *(const u32x4*)(Bw + (size_t)row*192 + kt*64 + co);
            *(u32x4*)(Bs + row*72 + co) = v;
        }
        __syncthreads();
        #pragma unroll
        for (int kk = 0; kk < 2; kk++) {
            int kg = kk*32 + kq*8;
            bf16x8 af[4], bfv[4];
            #pragma unroll
            for (int i = 0; i < 4; i++) {
                af[i]  = *(const bf16x8*)(As + (wm*64 + i*16 + lm)*72 + kg);
                bfv[i] = *(const bf16x8*)(Bs + (wn*64 + i*16 + lm)*72 + kg);
            }
            #pragma unroll
            for (int i = 0; i < 4; i++)
                #pragma unroll
                for (int j = 0; j < 4; j++)
                    acc[i][j] = __builtin_amdgcn_mfma_f32_16x16x32_bf16(af[i], bfv[j], acc[i][j], 0, 0, 0);
        }
    }
    int r0 = kq * 4;
    #pragma unroll
    for (int j = 0; j < 4; j++) {
        int n2 = wn*64 + j*16 + lm;
        int oc = (n2 < 96) ? n2 : n2 - 96;
        float bb = bias[((n2 < 96) ? 0 : 768) + wb*96 + oc];
        float ss = 0.f, tt = 0.f;
        if (LAYER == 0) { ss = sf[wb*96 + oc]; tt = tf[wb*96 + oc]; }
        __hip_bfloat16* Op = (n2 < 96) ? Or_ : Oi_;
        #pragma unroll
        for (int i = 0; i < 4; i++) {
            #pragma unroll
            for (int r = 0; r < 4; r++) {
                int p = mbase + wm*64 + i*16 + r0 + r;
                if (p < NPOS) {
                    float v = acc[i][j][r] + bb;
                    if (LAYER == 0) {
                        v = fmaxf(v*ss + tt, 0.0f);
                    } else {
                        v = (v > 0.01f) ? (v - 0.01f) : ((v < -0.01f) ? (v + 0.01f) : 0.0f);
                    }
                    Op[(size_t)p*CC + wb*96 + oc] = __float2bfloat16(v);
                }
            }
        }
    }
}

// ---------------- inverse W-DFT matrices (bf16) ----------------
__global__ __launch_bounds__(256) void aw_kernel(__hip_bfloat16* __restrict__ Aw) {
    int idx = blockIdx.x*256 + threadIdx.x;   // 384*96 = 36864
    if (idx >= 384*96) return;
    int w = idx / 96, f = idx - (idx/96)*96;
    const float rn = 0.05270462766947299f;
    float m = (f == 0) ? rn : ((f < FF) ? 2.0f*rn : 0.0f);
    int p = (int)(((long long)f * w) % 360);
    float ang = 6.283185307179586f / 360.0f * (float)p;
    float s_, c_; sincosf(ang, &s_, &c_);
    Aw[idx]          = __float2bfloat16(m * c_);
    Aw[384*96 + idx] = __float2bfloat16(-m * s_);
}

// ---------------- inverse rDFT along W via MFMA; out = idft + hln(bf16) + x ----------------
__global__ __launch_bounds__(256) void iwdft_mfma_kernel(
        const __hip_bfloat16* __restrict__ Zr, const __hip_bfloat16* __restrict__ Zi,
        const __hip_bfloat16* __restrict__ Aw,
        const __hip_bfloat16* __restrict__ hlnb,
        const float* __restrict__ xin, float* __restrict__ hout) {
    __shared__ __align__(16) unsigned short As[128*104];
    __shared__ __align__(16) unsigned short Bs[128*104];
    int h = blockIdx.z;
    int mbase = blockIdx.y * 128;   // w
    int nbase = blockIdx.x * 128;   // c
    int tid = threadIdx.x;
    int l = tid & 63, wv = tid >> 6;
    int wm = wv & 1, wn = wv >> 1;
    int lm = l & 15, kq = l >> 4;
    f32x4 acc[4][4] = {};
    #pragma unroll
    for (int ph = 0; ph < 2; ph++) {
        __syncthreads();
        for (int ch = tid; ch < 1536; ch += 256) {
            int row = ch / 12, co = (ch - row*12) * 8;
            u32x4 v = *(const u32x4*)(Aw + ((size_t)ph*384 + mbase + row)*96 + co);
            *(u32x4*)(As + row*104 + co) = v;
        }
        const __hip_bfloat16* Zp = ph ? Zi : Zr;
        for (int ch = tid; ch < 1536; ch += 256) {   // 96 f x 16 groups of 8 c
            int f = ch >> 4, cq = (ch & 15) * 8;
            unsigned int u[4] = {0u, 0u, 0u, 0u};
            if (f < FF) {
                u32x4 v = *(const u32x4*)(Zp + ((size_t)h*FF + f)*CC + nbase + cq);
                u[0] = v[0]; u[1] = v[1]; u[2] = v[2]; u[3] = v[3];
            }
            #pragma unroll
            for (int j = 0; j < 4; j++) {
                Bs[(cq + 2*j    )*104 + f] = (unsigned short)(u[j] & 0xffffu);
                Bs[(cq + 2*j + 1)*104 + f] = (unsigned short)(u[j] >> 16);
            }
        }
        __syncthreads();
        #pragma unroll
        for (int ks = 0; ks < 3; ks++) {
            int kg = ks*32 + kq*8;
            bf16x8 af[4], bfv[4];
            #pragma unroll
            for (int i = 0; i < 4; i++) {
                af[i]  = *(const bf16x8*)(As + (wm*64 + i*16 + lm)*104 + kg);
                bfv[i] = *(const bf16x8*)(Bs + (wn*64 + i*16 + lm)*104 + kg);
            }
            #pragma unroll
            for (int i = 0; i < 4; i++)
                #pragma unroll
                for (int j = 0; j < 4; j++)
                    acc[i][j] = __builtin_amdgcn_mfma_f32_16x16x32_bf16(af[i], bfv[j], acc[i][j], 0, 0, 0);
        }
    }
    int r0 = kq * 4;
    #pragma unroll
    for (int j = 0; j < 4; j++) {
        int col = nbase + wn*64 + j*16 + lm;
        #pragma unroll
        for (int i = 0; i < 4; i++) {
            int rowb = wm*64 + i*16 + r0;
            #pragma unroll
            for (int r = 0; r < 4; r++) {
                int wp = mbase + rowb + r;
                if (wp < WW) {
                    size_t idx = ((size_t)h*WW + wp)*CC + col;
                    hout[idx] = acc[i][j][r] + __bfloat162float(hlnb[idx]) + xin[idx];
                }
            }
        }
    }
}

// ---------------- tiled weight transpose + bf16 convert ----------------
__global__ __launch_bounds__(256) void transpose_bf16_kernel(const float* __restrict__ src,
        __hip_bfloat16* __restrict__ dst, int K, int N) {
    __shared__ float tile[32][33];
    int n0 = blockIdx.x * 32;
    int k0 = blockIdx.y * 32;
    int tx = threadIdx.x & 31;
    int ty = threadIdx.x >> 5;
    #pragma unroll
    for (int r = 0; r < 32; r += 8) {
        tile[ty + r][tx] = src[(size_t)(k0 + ty + r) * N + n0 + tx];
    }
    __syncthreads();
    #pragma unroll
    for (int r = 0; r < 32; r += 8) {
        dst[(size_t)(n0 + ty + r) * K + k0 + tx] = __float2bfloat16(tile[tx][ty + r]);
    }
}

// ---------------- bf16 MFMA GEMM, 256x256 tile, BK=64, 8 waves, 8-phase schedule ----------------
// Stage units per K-tile (8 loads/thread): B-half0(2), B-half1(2), A-slice0..3(1 each;
// slice p = rows {32p..32p+31} U {128+32p..+31} -- exactly phase p's A consumption for both wm).
// Phase p of tile kt: issue unit p of tile kt+1 -> s_waitcnt vmcnt(N) (N = loads not yet needed:
// steady 5/6/7/8, drain 3/2/1/0) -> barrier (validates region across waves) -> ds_read -> 16 MFMA.
// Tile-end barrier keeps tile kt+1's staging from overwriting buf[d] while still being read.
// MODE 0: out = bf16(gelu((A@B + bias)*s + t)) ; MODE 1: out = A@B + bias + resid (fp32)
template<int MODE>
__global__ __launch_bounds__(512, 2) void gemm256_kernel(
        const __hip_bfloat16* __restrict__ A,
        const __hip_bfloat16* __restrict__ Bt,
        int M, int K, int N,
        const float* __restrict__ bias,
        const float* __restrict__ sv, const float* __restrict__ tv,
        const float* resid, void* out) {
    __shared__ __align__(16) unsigned short SH[65536];    // 128 KB
    unsigned short* Asb = SH;            // [2][256*64]
    unsigned short* Bsb = SH + 32768;    // [2][256*64]
    int tid = threadIdx.x;
    int nbase = blockIdx.x * 256;
    int mbase = blockIdx.y * 256;
    int l = tid & 63, wv = tid >> 6;     // 8 waves
    int wm = wv & 1, wn = wv >> 1;       // wm 0..1 (128 rows), wn 0..3 (64 cols)
    int lm = l & 15, kq = l >> 4;
    f32x4 acc[8][4] = {};
    int nkt = K >> 6;

    auto gload = [&](const __hip_bfloat16* g, unsigned short* lds) {
        __builtin_amdgcn_global_load_lds(
            (const __attribute__((address_space(1))) void*)(unsigned long long)(uintptr_t)g,
            (__attribute__((address_space(3))) void*)(unsigned long long)(uintptr_t)lds,
            16, 0, 0);
    };
    auto stageB = [&](int d, int kt, int half) {     // 2 loads/thread
        int kb = kt << 6;
        #pragma unroll
        for (int i = 0; i < 2; i++) {
            int ch = half*1024 + i*512 + tid;        // 0..2047
            int row = ch >> 3;
            int sl = ch & 7;
            int kg = (sl ^ (row & 7)) << 3;
            gload(Bt + (size_t)(nbase + row) * K + kb + kg, Bsb + d*16384 + ch*8);
        }
    };
    auto stageA = [&](int d, int kt, int p) {        // 1 load/thread
        int kb = kt << 6;
        int rl = tid >> 3;                           // 0..63
        int row = (rl < 32) ? (p*32 + rl) : (96 + p*32 + rl);   // {32p..+31} U {128+32p..+31}
        int sl = tid & 7;
        int kg = (sl ^ (row & 7)) << 3;
        int am = mbase + row; if (am >= M) am = M - 1;
        gload(A + (size_t)am * K + kb + kg, Asb + d*16384 + row*64 + sl*8);
    };

#define GPHASE(P, VM, STAGECODE)                                                          \
    {                                                                                     \
        STAGECODE;                                                                        \
        asm volatile("s_waitcnt vmcnt(" #VM ")" ::: "memory");                            \
        __builtin_amdgcn_s_barrier();                                                     \
        asm volatile("" ::: "memory");                                                    \
        int ra0 = wm*128 + (2*(P))*16 + lm;                                               \
        int ra1 = ra0 + 16;                                                               \
        bf16x8 a00 = *(const bf16x8*)(Ab + ra0*64 + (((kq    ) ^ (ra0&7))<<3));           \
        bf16x8 a01 = *(const bf16x8*)(Ab + ra0*64 + (((4 + kq) ^ (ra0&7))<<3));           \
        bf16x8 a10 = *(const bf16x8*)(Ab + ra1*64 + (((kq    ) ^ (ra1&7))<<3));           \
        bf16x8 a11 = *(const bf16x8*)(Ab + ra1*64 + (((4 + kq) ^ (ra1&7))<<3));           \
        bf16x8 bv[4][2];                                                                  \
        _Pragma("unroll")                                                                 \
        for (int j = 0; j < 4; j++) {                                                     \
            int rb = wn*64 + j*16 + lm;                                                   \
            bv[j][0] = *(const bf16x8*)(Bb + rb*64 + (((kq    ) ^ (rb&7))<<3));           \
            bv[j][1] = *(const bf16x8*)(Bb + rb*64 + (((4 + kq) ^ (rb&7))<<3));           \
        }                                                                                 \
        __builtin_amdgcn_s_setprio(1);                                                    \
        _Pragma("unroll")                                                                 \
        for (int j = 0; j < 4; j++) {                                                     \
            acc[2*(P)][j]   = __builtin_amdgcn_mfma_f32_16x16x32_bf16(a00, bv[j][0], acc[2*(P)][j],   0,0,0); \
            acc[2*(P)][j]   = __builtin_amdgcn_mfma_f32_16x16x32_bf16(a01, bv[j][1], acc[2*(P)][j],   0,0,0); \
            acc[2*(P)+1][j] = __builtin_amdgcn_mfma_f32_16x16x32_bf16(a10, bv[j][0], acc[2*(P)+1][j], 0,0,0); \
            acc[2*(P)+1][j] = __builtin_amdgcn_mfma_f32_16x16x32_bf16(a11, bv[j][1], acc[2*(P)+1][j], 0,0,0); \
        }                                                                                 \
        __builtin_amdgcn_s_setprio(0);                                                    \
    }

    // prologue: stage tile 0 fully into buf 0 (order: B0,B1,A0..A3 -> 8 loads)
    stageB(0, 0, 0); stageB(0, 0, 1);
    stageA(0, 0, 0); stageA(0, 0, 1); stageA(0, 0, 2); stageA(0, 0, 3);
    for (int kt = 0; kt < nkt; kt++) {
        int d = kt & 1;
        const unsigned short* Ab = Asb + d*16384;
        const unsigned short* Bb = Bsb + d*16384;
        if (kt + 1 < nkt) {
            int dn = d ^ 1, kn = kt + 1;
            GPHASE(0, 5, stageB(dn, kn, 0))
            GPHASE(1, 6, stageB(dn, kn, 1))
            GPHASE(2, 7, stageA(dn, kn, 0); stageA(dn, kn, 1))
            GPHASE(3, 8, stageA(dn, kn, 2); stageA(dn, kn, 3))
        } else {
            GPHASE(0, 3, (void)0)
            GPHASE(1, 2, (void)0)
            GPHASE(2, 1, (void)0)
            GPHASE(3, 0, (void)0)
        }
        asm volatile("" ::: "memory");
        __builtin_amdgcn_s_barrier();    // tile end: buf d reads done before it is re-staged
    }
#undef GPHASE

    int r0 = kq * 4;
    if (MODE == 0) {
        // epilogue: gelu+mod -> bf16 tile in LDS [256][256], then coalesced store
        #pragma unroll
        for (int j = 0; j < 4; j++) {
            int col = wn*64 + j*16 + lm;
            int gcol = nbase + col;
            float bb = bias[gcol];
            float ss = sv[gcol], tt = tv[gcol];
            #pragma unroll
            for (int i = 0; i < 8; i++) {
                int rowb = wm*128 + i*16 + r0;
                #pragma unroll
                for (int r = 0; r < 4; r++) {
                    float v = gelu_f((acc[i][j][r] + bb)*ss + tt);
                    __hip_bfloat16 hb = __float2bfloat16(v);
                    SH[(rowb + r)*256 + col] = *reinterpret_cast<unsigned short*>(&hb);
                }
            }
        }
        __syncthreads();
        #pragma unroll
        for (int it = 0; it < 16; it++) {
            int chunk = it*512 + tid;    // 8192 chunks of 16B (256 rows x 32)
            int row = chunk >> 5;
            int c8 = chunk & 31;
            int mr = mbase + row;
            if (mr < M) {
                *(u32x4*)((__hip_bfloat16*)out + (size_t)mr*N + nbase + c8*8) =
                    *(const u32x4*)(SH + row*256 + c8*8);
            }
        }
    } else {
        #pragma unroll
        for (int j = 0; j < 4; j++) {
            int col = nbase + wn*64 + j*16 + lm;
            float bb = bias[col];
            #pragma unroll
            for (int i = 0; i < 8; i++) {
                int rowb = mbase + wm*128 + i*16 + r0;
                #pragma unroll
                for (int r = 0; r < 4; r++) {
                    int row = rowb + r;
                    if (row < M) {
                        float v = acc[i][j][r] + bb;
                        ((float*)out)[(size_t)row*N + col] = v + resid[(size_t)row*N + col];
                    }
                }
            }
        }
    }
}

extern "C" void kernel_launch(void* const* d_in, const int* in_sizes, int n_in,
                              void* d_out, int out_size, void* d_ws, size_t ws_size,
                              hipStream_t stream) {
    const float* x     = (const float*)d_in[0];
    const float* emb   = (const float*)d_in[1];
    const float* n1w   = (const float*)d_in[2];
    const float* n1b   = (const float*)d_in[3];
    const float* n2w   = (const float*)d_in[4];
    const float* n2b   = (const float*)d_in[5];
    const float* w1    = (const float*)d_in[6];
    const float* b1    = (const float*)d_in[7];
    const float* w2    = (const float*)d_in[8];
    const float* b2    = (const float*)d_in[9];
    const float* fs_w0 = (const float*)d_in[10];
    const float* fs_b0 = (const float*)d_in[11];
    const float* fs_w1 = (const float*)d_in[12];
    const float* fs_b1 = (const float*)d_in[13];
    const float* fc1w  = (const float*)d_in[14];
    const float* fc1b  = (const float*)d_in[15];
    const float* fc2w  = (const float*)d_in[16];
    const float* fc2b  = (const float*)d_in[17];
    const float* ms_w0 = (const float*)d_in[18];
    const float* ms_b0 = (const float*)d_in[19];
    const float* ms_w1 = (const float*)d_in[20];
    const float* ms_b1 = (const float*)d_in[21];
    float* out = (float*)d_out;
    (void)in_sizes; (void)n_in; (void)out_size; (void)ws_size;

    char* wsb = (char*)d_ws;
    size_t off = 0;
    auto alloc = [&](size_t nbytes) -> void* {
        void* p = wsb + off;
        off += (nbytes + 255) & ~(size_t)255;
        return p;
    };
    float* s_f  = (float*)alloc(768*4);
    float* t_f  = (float*)alloc(768*4);
    float* s_m  = (float*)alloc(3072*4);
    float* t_m  = (float*)alloc(3072*4);
    float* midf = (float*)alloc(1536*4);
    float* midm = (float*)alloc(6144*4);
    __hip_bfloat16* Aw  = (__hip_bfloat16*)alloc((size_t)2*384*96*2);
    __hip_bfloat16* Ew  = (__hip_bfloat16*)alloc((size_t)192*384*2);
    __hip_bfloat16* Eh  = (__hip_bfloat16*)alloc((size_t)4*192*384*2);
    __hip_bfloat16* Bt1 = (__hip_bfloat16*)alloc((size_t)8*192*192*2);
    __hip_bfloat16* Bt2 = (__hip_bfloat16*)alloc((size_t)8*192*192*2);
    __hip_bfloat16* Yrb = (__hip_bfloat16*)alloc((size_t)NPOS*CC*2);
    __hip_bfloat16* Yib = (__hip_bfloat16*)alloc((size_t)NPOS*CC*2);
    __hip_bfloat16* Zrb = (__hip_bfloat16*)alloc((size_t)NPOS*CC*2);
    __hip_bfloat16* Zib = (__hip_bfloat16*)alloc((size_t)NPOS*CC*2);
    __hip_bfloat16* wT1  = (__hip_bfloat16*)alloc((size_t)CC*LAT*2);
    __hip_bfloat16* wT2  = (__hip_bfloat16*)alloc((size_t)CC*LAT*2);
    __hip_bfloat16* h2   = (__hip_bfloat16*)alloc((size_t)NROW*CC*2);
    __hip_bfloat16* hmid = (__hip_bfloat16*)alloc((size_t)NROW*LAT*2);
    // h_ln (bf16) aliases h2: lifetimes are disjoint
    __hip_bfloat16* hlnb = h2;

    // 1. modulation scale/shift vectors + twiddle/weight matrices
    mod_a_kernel<<<30, 256, 0, stream>>>(emb, fs_w0, fs_b0, ms_w0, ms_b0, midf, midm);
    mod_b_kernel<<<120, 512, 0, stream>>>(midf, midm, fs_w1, fs_b1, ms_w1, ms_b1,
                                          s_f, t_f, s_m, t_m);
    aw_kernel<<<144, 256, 0, stream>>>(Aw);
    ew_kernel<<<288, 256, 0, stream>>>(Ew);
    eh_kernel<<<1152, 256, 0, stream>>>(Eh);
    bdw_kernel<<<1152, 256, 0, stream>>>(w1, Bt1);
    bdw_kernel<<<1152, 256, 0, stream>>>(w2, Bt2);
    // 2. LN1 -> hlnb (bf16)
    ln_bf16_kernel<<<NROW/4, 256, 0, stream>>>(x, n1w, n1b, hlnb);
    // 3. weight convert+transpose
    transpose_bf16_kernel<<<dim3(LAT/32, CC/32), 256, 0, stream>>>(fc1w, wT1, 768, 3072);
    transpose_bf16_kernel<<<dim3(CC/32, LAT/32), 256, 0, stream>>>(fc2w, wT2, 3072, 768);

    // 4. filter path, all MFMA, bf16 intermediates
    transform_mfma<0><<<dim3(6, 1, 180), 256, 0, stream>>>(Ew, hlnb, nullptr, Yrb, Yib);
    transform_mfma<1><<<dim3(6, 2, 91), 256, 0, stream>>>(Eh, Yrb, Yib, Zrb, Zib);               // fwd
    bd_mfma_kernel<0><<<dim3(128, 8), 384, 0, stream>>>(Zrb, Zib, Bt1, b1, s_f, t_f, Yrb, Yib);
    bd_mfma_kernel<1><<<dim3(128, 8), 384, 0, stream>>>(Yrb, Yib, Bt2, b2, nullptr, nullptr, Zrb, Zib);
    transform_mfma<1><<<dim3(6, 2, 91), 256, 0, stream>>>(Eh + (size_t)2*192*384, Zrb, Zib, Yrb, Yib);  // inv
    iwdft_mfma_kernel<<<dim3(6, 3, 180), 256, 0, stream>>>(Yrb, Yib, Aw, hlnb, x, out);

    // 5. MLP path (d_out holds h; update in place)
    ln_bf16_kernel<<<NROW/4, 256, 0, stream>>>(out, n2w, n2b, h2);
    gemm256_kernel<0><<<dim3(LAT/256, (NROW+255)/256), 512, 0, stream>>>(
        h2, wT1, NROW, CC, LAT, fc1b, s_m, t_m, nullptr, hmid);
    gemm256_kernel<1><<<dim3(CC/256, (NROW+255)/256), 512, 0, stream>>>(
        hmid, wT2, NROW, LAT, CC, fc2b, nullptr, nullptr, out, out);
}

// Round 14
// 1901.392 us; speedup vs baseline: 2.1255x; 2.1255x over previous
//
#include <hip/hip_runtime.h>
#include <hip/hip_bf16.h>
#include <math.h>

// Problem constants
#define HH 180
#define WW 360
#define CC 768
#define FF 91          // kept W-frequencies (km = 91)
#define NPOS (HH*FF)   // 16380 frequency positions
#define NROW (HH*WW)   // 64800 spatial rows
#define LAT 3072

typedef __attribute__((ext_vector_type(8))) short bf16x8;
typedef __attribute__((ext_vector_type(4))) float f32x4;
typedef __attribute__((ext_vector_type(4))) unsigned int u32x4;

__device__ __forceinline__ float gelu_f(float x) {
    return 0.5f * x * (1.0f + erff(x * 0.7071067811865476f));
}

// ---------------- modulation stage A ----------------
__global__ __launch_bounds__(256) void mod_a_kernel(
        const float* __restrict__ e,
        const float* __restrict__ fs_w0, const float* __restrict__ fs_b0,
        const float* __restrict__ ms_w0, const float* __restrict__ ms_b0,
        float* __restrict__ mid_f, float* __restrict__ mid_m) {
    __shared__ float es[64];
    int t = threadIdx.x;
    if (t < 64) es[t] = e[t];
    __syncthreads();
    int j = blockIdx.x * 256 + t;
    if (j < 1536) {
        float a = fs_b0[j];
        #pragma unroll 8
        for (int k = 0; k < 64; k++) a += es[k] * fs_w0[k*1536 + j];
        mid_f[j] = gelu_f(a);
    } else {
        int jm = j - 1536;
        float a = ms_b0[jm];
        #pragma unroll 8
        for (int k = 0; k < 64; k++) a += es[k] * ms_w0[k*6144 + jm];
        mid_m[jm] = gelu_f(a);
    }
}

// ---------------- modulation stage B ----------------
__global__ __launch_bounds__(512) void mod_b_kernel(
        const float* __restrict__ mid_f, const float* __restrict__ mid_m,
        const float* __restrict__ fs_w1, const float* __restrict__ fs_b1,
        const float* __restrict__ ms_w1, const float* __restrict__ ms_b1,
        float* __restrict__ s_f, float* __restrict__ t_f,
        float* __restrict__ s_m, float* __restrict__ t_m) {
    __shared__ float red[8*64];
    int t = threadIdx.x;
    int g = t >> 6;
    int jl = t & 63;
    int blk = blockIdx.x;
    if (blk < 24) {
        int jo = blk*64 + jl;
        const int N = 1536, NQ = 192;
        float a = 0.f;
        const float* w = fs_w1 + (size_t)(g*NQ)*N + jo;
        for (int j = 0; j < NQ; j++) a += mid_f[g*NQ + j] * w[(size_t)j*N];
        red[t] = a;
        __syncthreads();
        if (t < 64) {
            float s = fs_b1[jo];
            #pragma unroll
            for (int q = 0; q < 8; q++) s += red[q*64 + jl];
            if (jo < 768) s_f[jo] = 1.0f + s;
            else          t_f[jo - 768] = s;
        }
    } else {
        int jo = (blk - 24)*64 + jl;
        const int N = 6144, NQ = 768;
        float a = 0.f;
        const float* w = ms_w1 + (size_t)(g*NQ)*N + jo;
        for (int j = 0; j < NQ; j++) a += mid_m[g*NQ + j] * w[(size_t)j*N];
        red[t] = a;
        __syncthreads();
        if (t < 64) {
            float s = ms_b1[jo];
            #pragma unroll
            for (int q = 0; q < 8; q++) s += red[q*64 + jl];
            if (jo < 3072) s_m[jo] = 1.0f + s;
            else           t_m[jo - 3072] = s;
        }
    }
}

// ---------------- LayerNorm bf16 out ----------------
__global__ __launch_bounds__(256) void ln_bf16_kernel(const float* __restrict__ in,
        const float* __restrict__ w, const float* __restrict__ b,
        __hip_bfloat16* __restrict__ out) {
    int row = blockIdx.x*4 + (threadIdx.x >> 6);
    int l = threadIdx.x & 63;
    const float* p = in + (size_t)row*CC;
    float v[12]; float s = 0.f, sq = 0.f;
    #pragma unroll
    for (int i = 0; i < 12; i++) { float tv = p[l + 64*i]; v[i] = tv; s += tv; sq += tv*tv; }
    #pragma unroll
    for (int m = 1; m < 64; m <<= 1) { s += __shfl_xor(s, m); sq += __shfl_xor(sq, m); }
    float mean = s * (1.0f/768.0f);
    float var  = sq * (1.0f/768.0f) - mean*mean;
    float rstd = rsqrtf(var + 1e-5f);
    __hip_bfloat16* o = out + (size_t)row*CC;
    #pragma unroll
    for (int i = 0; i < 12; i++) { int c = l + 64*i; o[c] = __float2bfloat16((v[i]-mean)*rstd*w[c] + b[c]); }
}

// ---------------- twiddle matrices ----------------
__global__ __launch_bounds__(256) void ew_kernel(__hip_bfloat16* __restrict__ Ew) {
    int idx = blockIdx.x*256 + threadIdx.x;
    if (idx >= 192*384) return;
    int r = idx / 384, w = idx - (idx/384)*384;
    int f = (r < 96) ? r : r - 96;
    const float rn = 0.05270462766947299f;  // 1/sqrt(360)
    float v = 0.f;
    if (f < FF && w < WW) {
        int p = (f * w) % 360;
        float ang = 6.283185307179586f/360.0f * (float)p;
        float s_, c_; sincosf(ang, &s_, &c_);
        v = (r < 96) ? c_*rn : -s_*rn;
    }
    Ew[idx] = __float2bfloat16(v);
}

__global__ __launch_bounds__(256) void eh_kernel(__hip_bfloat16* __restrict__ Eh) {
    int idx = blockIdx.x*256 + threadIdx.x;
    if (idx >= 4*192*384) return;
    int sp = idx / (192*384);
    int rem = idx - sp*(192*384);
    int t = rem / 384, k = rem - (rem/384)*384;
    int sig = sp >> 1, plane = sp & 1;
    float s = (sig == 0) ? -1.f : 1.f;
    int h = (k < 192) ? k : k - 192;
    const float rnh = 0.07453559924999299f;  // 1/sqrt(180)
    float v = 0.f;
    if (t < HH && h < HH) {
        int p = (t * h) % 180;
        float ang = 6.283185307179586f/180.0f * (float)p;
        float s_, c_; sincosf(ang, &s_, &c_);
        float C = c_*rnh, S = s_*rnh;
        if (plane == 0) v = (k < 192) ? C : -s*S;
        else            v = (k < 192) ? s*S : C;
    }
    Eh[idx] = __float2bfloat16(v);
}

// ---------------- bd stacked-complex weight pack ----------------
__global__ __launch_bounds__(256) void bdw_kernel(const float* __restrict__ w,
        __hip_bfloat16* __restrict__ Bt) {
    int idx = blockIdx.x*256 + threadIdx.x;   // 8*192*192 = 294912
    if (idx >= 8*192*192) return;
    int wb = idx / (192*192);
    int rem = idx - wb*(192*192);
    int n2 = rem / 192, k2 = rem - (rem/192)*192;
    int k = (k2 < 96) ? k2 : k2 - 96;
    int oc = (n2 < 96) ? n2 : n2 - 96;
    float w0 = w[((size_t)wb*96 + k)*96 + oc];
    float w1v = w[((size_t)(8 + wb)*96 + k)*96 + oc];
    float v;
    if (n2 < 96) v = (k2 < 96) ? w0 : -w1v;
    else         v = (k2 < 96) ? w1v : w0;
    Bt[idx] = __float2bfloat16(v);
}

// ---------------- MFMA transform: C[192 rows][128 c] = A[192][384] @ B[384][c], all bf16 I/O ----------------
template<int MODE>
__global__ __launch_bounds__(256) void transform_mfma(
        const __hip_bfloat16* __restrict__ Amat,
        const __hip_bfloat16* __restrict__ B0, const __hip_bfloat16* __restrict__ B1,
        __hip_bfloat16* __restrict__ O0, __hip_bfloat16* __restrict__ O1) {
    __shared__ __align__(16) unsigned short As[192*72];
    __shared__ __align__(16) unsigned short Bs[128*72];
    int nbase = blockIdx.x * 128;
    int bat = blockIdx.z;
    int tid = threadIdx.x;
    int l = tid & 63, wv = tid >> 6;
    int wm = wv & 1, wn = wv >> 1;
    int lm = l & 15, kq = l >> 4;
    const __hip_bfloat16* Ab = Amat + (MODE == 1 ? (size_t)blockIdx.y*192*384 : 0);
    f32x4 acc[6][4] = {};
    for (int kt = 0; kt < 6; kt++) {
        int kb = kt*64;
        __syncthreads();
        #pragma unroll
        for (int it = 0; it < 6; it++) {
            int ch = it*256 + tid;
            int row = ch >> 3, co = (ch & 7) * 8;
            u32x4 v = *(const u32x4*)(Ab + (size_t)row*384 + kb + co);
            *(u32x4*)(As + row*72 + co) = v;
        }
        #pragma unroll
        for (int it = 0; it < 4; it++) {
            int idx = it*256 + tid;
            int row = idx >> 4;
            int cq = (idx & 15) * 8;
            int k = kb + row;
            unsigned int u[4] = {0u, 0u, 0u, 0u};
            if (MODE == 0) {
                if (k < WW) {
                    u32x4 v = *(const u32x4*)(B0 + (size_t)bat*WW*CC + (size_t)k*CC + nbase + cq);
                    u[0] = v[0]; u[1] = v[1]; u[2] = v[2]; u[3] = v[3];
                }
            } else {
                if (k < 192) {
                    if (k < HH) {
                        u32x4 v = *(const u32x4*)(B0 + (size_t)k*FF*CC + (size_t)bat*CC + nbase + cq);
                        u[0] = v[0]; u[1] = v[1]; u[2] = v[2]; u[3] = v[3];
                    }
                } else {
                    int h2 = k - 192;
                    if (h2 < HH) {
                        u32x4 v = *(const u32x4*)(B1 + (size_t)h2*FF*CC + (size_t)bat*CC + nbase + cq);
                        u[0] = v[0]; u[1] = v[1]; u[2] = v[2]; u[3] = v[3];
                    }
                }
            }
            #pragma unroll
            for (int j = 0; j < 4; j++) {
                Bs[(cq + 2*j    )*72 + row] = (unsigned short)(u[j] & 0xffffu);
                Bs[(cq + 2*j + 1)*72 + row] = (unsigned short)(u[j] >> 16);
            }
        }
        __syncthreads();
        #pragma unroll
        for (int kk = 0; kk < 2; kk++) {
            int kg = kk*32 + kq*8;
            bf16x8 af[6], bfv[4];
            #pragma unroll
            for (int i = 0; i < 6; i++)
                af[i] = *(const bf16x8*)(As + (wm*96 + i*16 + lm)*72 + kg);
            #pragma unroll
            for (int j = 0; j < 4; j++)
                bfv[j] = *(const bf16x8*)(Bs + (wn*64 + j*16 + lm)*72 + kg);
            #pragma unroll
            for (int i = 0; i < 6; i++)
                #pragma unroll
                for (int j = 0; j < 4; j++)
                    acc[i][j] = __builtin_amdgcn_mfma_f32_16x16x32_bf16(af[i], bfv[j], acc[i][j], 0, 0, 0);
        }
    }
    int r0 = kq * 4;
    #pragma unroll
    for (int j = 0; j < 4; j++) {
        int col = nbase + wn*64 + j*16 + lm;
        #pragma unroll
        for (int i = 0; i < 6; i++) {
            #pragma unroll
            for (int r = 0; r < 4; r++) {
                int row = wm*96 + i*16 + r0 + r;
                __hip_bfloat16 hv = __float2bfloat16(acc[i][j][r]);
                if (MODE == 0) {
                    if (row < 96) {
                        if (row < FF) O0[(size_t)bat*FF*CC + (size_t)row*CC + col] = hv;
                    } else {
                        int f2 = row - 96;
                        if (f2 < FF) O1[(size_t)bat*FF*CC + (size_t)f2*CC + col] = hv;
                    }
                } else {
                    if (row < HH) {
                        __hip_bfloat16* Op = blockIdx.y ? O1 : O0;
                        Op[(size_t)row*FF*CC + (size_t)bat*CC + col] = hv;
                    }
                }
            }
        }
    }
}

// ---------------- block-diagonal complex matmul via MFMA (stacked-complex GEMM), bf16 I/O ----------------
template<int LAYER>
__global__ __launch_bounds__(384) void bd_mfma_kernel(
        const __hip_bfloat16* __restrict__ Ir, const __hip_bfloat16* __restrict__ Ii,
        const __hip_bfloat16* __restrict__ Bt,
        const float* __restrict__ bias,
        const float* __restrict__ sf, const float* __restrict__ tf,
        __hip_bfloat16* __restrict__ Or_, __hip_bfloat16* __restrict__ Oi_) {
    __shared__ __align__(16) unsigned short As[128*72];
    __shared__ __align__(16) unsigned short Bs[192*72];
    int mbase = blockIdx.x * 128;
    int wb = blockIdx.y;
    int tid = threadIdx.x;
    int l = tid & 63, wv = tid >> 6;      // 6 waves
    int wm = wv & 1, wn = wv >> 1;
    int lm = l & 15, kq = l >> 4;
    const __hip_bfloat16* Bw = Bt + (size_t)wb*192*192;
    f32x4 acc[4][4] = {};
    for (int kt = 0; kt < 3; kt++) {
        __syncthreads();
        for (int ch = tid; ch < 1024; ch += 384) {
            int row = ch >> 3, q = ch & 7;
            int k2 = kt*64 + q*8;
            int p = mbase + row; if (p >= NPOS) p = NPOS - 1;
            const __hip_bfloat16* src = (k2 < 96) ? (Ir + (size_t)p*CC + wb*96 + k2)
                                                  : (Ii + (size_t)p*CC + wb*96 + (k2 - 96));
            *(u32x4*)(As + row*72 + q*8) = *(const u32x4*)src;
        }
        for (int ch = tid; ch < 1536; ch += 384) {
            int row = ch >> 3, co = (ch & 7) * 8;
            u32x4 v = *(const u32x4*)(Bw + (size_t)row*192 + kt*64 + co);
            *(u32x4*)(Bs + row*72 + co) = v;
        }
        __syncthreads();
        #pragma unroll
        for (int kk = 0; kk < 2; kk++) {
            int kg = kk*32 + kq*8;
            bf16x8 af[4], bfv[4];
            #pragma unroll
            for (int i = 0; i < 4; i++) {
                af[i]  = *(const bf16x8*)(As + (wm*64 + i*16 + lm)*72 + kg);
                bfv[i] = *(const bf16x8*)(Bs + (wn*64 + i*16 + lm)*72 + kg);
            }
            #pragma unroll
            for (int i = 0; i < 4; i++)
                #pragma unroll
                for (int j = 0; j < 4; j++)
                    acc[i][j] = __builtin_amdgcn_mfma_f32_16x16x32_bf16(af[i], bfv[j], acc[i][j], 0, 0, 0);
        }
    }
    int r0 = kq * 4;
    #pragma unroll
    for (int j = 0; j < 4; j++) {
        int n2 = wn*64 + j*16 + lm;
        int oc = (n2 < 96) ? n2 : n2 - 96;
        float bb = bias[((n2 < 96) ? 0 : 768) + wb*96 + oc];
        float ss = 0.f, tt = 0.f;
        if (LAYER == 0) { ss = sf[wb*96 + oc]; tt = tf[wb*96 + oc]; }
        __hip_bfloat16* Op = (n2 < 96) ? Or_ : Oi_;
        #pragma unroll
        for (int i = 0; i < 4; i++) {
            #pragma unroll
            for (int r = 0; r < 4; r++) {
                int p = mbase + wm*64 + i*16 + r0 + r;
                if (p < NPOS) {
                    float v = acc[i][j][r] + bb;
                    if (LAYER == 0) {
                        v = fmaxf(v*ss + tt, 0.0f);
                    } else {
                        v = (v > 0.01f) ? (v - 0.01f) : ((v < -0.01f) ? (v + 0.01f) : 0.0f);
                    }
                    Op[(size_t)p*CC + wb*96 + oc] = __float2bfloat16(v);
                }
            }
        }
    }
}

// ---------------- inverse W-DFT matrices (bf16) ----------------
__global__ __launch_bounds__(256) void aw_kernel(__hip_bfloat16* __restrict__ Aw) {
    int idx = blockIdx.x*256 + threadIdx.x;   // 384*96 = 36864
    if (idx >= 384*96) return;
    int w = idx / 96, f = idx - (idx/96)*96;
    const float rn = 0.05270462766947299f;
    float m = (f == 0) ? rn : ((f < FF) ? 2.0f*rn : 0.0f);
    int p = (int)(((long long)f * w) % 360);
    float ang = 6.283185307179586f / 360.0f * (float)p;
    float s_, c_; sincosf(ang, &s_, &c_);
    Aw[idx]          = __float2bfloat16(m * c_);
    Aw[384*96 + idx] = __float2bfloat16(-m * s_);
}

// ---------------- inverse rDFT along W via MFMA; out = idft + hln(bf16) + x ----------------
__global__ __launch_bounds__(256) void iwdft_mfma_kernel(
        const __hip_bfloat16* __restrict__ Zr, const __hip_bfloat16* __restrict__ Zi,
        const __hip_bfloat16* __restrict__ Aw,
        const __hip_bfloat16* __restrict__ hlnb,
        const float* __restrict__ xin, float* __restrict__ hout) {
    __shared__ __align__(16) unsigned short As[128*104];
    __shared__ __align__(16) unsigned short Bs[128*104];
    int h = blockIdx.z;
    int mbase = blockIdx.y * 128;   // w
    int nbase = blockIdx.x * 128;   // c
    int tid = threadIdx.x;
    int l = tid & 63, wv = tid >> 6;
    int wm = wv & 1, wn = wv >> 1;
    int lm = l & 15, kq = l >> 4;
    f32x4 acc[4][4] = {};
    #pragma unroll
    for (int ph = 0; ph < 2; ph++) {
        __syncthreads();
        for (int ch = tid; ch < 1536; ch += 256) {
            int row = ch / 12, co = (ch - row*12) * 8;
            u32x4 v = *(const u32x4*)(Aw + ((size_t)ph*384 + mbase + row)*96 + co);
            *(u32x4*)(As + row*104 + co) = v;
        }
        const __hip_bfloat16* Zp = ph ? Zi : Zr;
        for (int ch = tid; ch < 1536; ch += 256) {   // 96 f x 16 groups of 8 c
            int f = ch >> 4, cq = (ch & 15) * 8;
            unsigned int u[4] = {0u, 0u, 0u, 0u};
            if (f < FF) {
                u32x4 v = *(const u32x4*)(Zp + ((size_t)h*FF + f)*CC + nbase + cq);
                u[0] = v[0]; u[1] = v[1]; u[2] = v[2]; u[3] = v[3];
            }
            #pragma unroll
            for (int j = 0; j < 4; j++) {
                Bs[(cq + 2*j    )*104 + f] = (unsigned short)(u[j] & 0xffffu);
                Bs[(cq + 2*j + 1)*104 + f] = (unsigned short)(u[j] >> 16);
            }
        }
        __syncthreads();
        #pragma unroll
        for (int ks = 0; ks < 3; ks++) {
            int kg = ks*32 + kq*8;
            bf16x8 af[4], bfv[4];
            #pragma unroll
            for (int i = 0; i < 4; i++) {
                af[i]  = *(const bf16x8*)(As + (wm*64 + i*16 + lm)*104 + kg);
                bfv[i] = *(const bf16x8*)(Bs + (wn*64 + i*16 + lm)*104 + kg);
            }
            #pragma unroll
            for (int i = 0; i < 4; i++)
                #pragma unroll
                for (int j = 0; j < 4; j++)
                    acc[i][j] = __builtin_amdgcn_mfma_f32_16x16x32_bf16(af[i], bfv[j], acc[i][j], 0, 0, 0);
        }
    }
    int r0 = kq * 4;
    #pragma unroll
    for (int j = 0; j < 4; j++) {
        int col = nbase + wn*64 + j*16 + lm;
        #pragma unroll
        for (int i = 0; i < 4; i++) {
            int rowb = wm*64 + i*16 + r0;
            #pragma unroll
            for (int r = 0; r < 4; r++) {
                int wp = mbase + rowb + r;
                if (wp < WW) {
                    size_t idx = ((size_t)h*WW + wp)*CC + col;
                    hout[idx] = acc[i][j][r] + __bfloat162float(hlnb[idx]) + xin[idx];
                }
            }
        }
    }
}

// ---------------- tiled weight transpose + bf16 convert ----------------
__global__ __launch_bounds__(256) void transpose_bf16_kernel(const float* __restrict__ src,
        __hip_bfloat16* __restrict__ dst, int K, int N) {
    __shared__ float tile[32][33];
    int n0 = blockIdx.x * 32;
    int k0 = blockIdx.y * 32;
    int tx = threadIdx.x & 31;
    int ty = threadIdx.x >> 5;
    #pragma unroll
    for (int r = 0; r < 32; r += 8) {
        tile[ty + r][tx] = src[(size_t)(k0 + ty + r) * N + n0 + tx];
    }
    __syncthreads();
    #pragma unroll
    for (int r = 0; r < 32; r += 8) {
        dst[(size_t)(n0 + ty + r) * K + k0 + tx] = __float2bfloat16(tile[tx][ty + r]);
    }
}

// ---------------- bf16 MFMA GEMM, 256x256 tile, BK=64, 8 waves (2M x 4N), 2-phase dbuf ----------------
// 1D grid + bijective XCD-chunked swizzle (T1/m204): blocks resident on one XCD cover a
// contiguous logical-tile range -> A-panels (shared by nx consecutive tiles) stay L2-local.
// LDS: A dbuf 2x[256][64] + B dbuf 2x[256][64] = 128 KB; XOR-swizzle slot = kchunk ^ (row&7)
// MODE 0: out = bf16(gelu((A@B + bias)*s + t)), LDS-staged coalesced store
// MODE 1: out = A@B + bias + resid (fp32)
template<int MODE>
__global__ __launch_bounds__(512, 2) void gemm256_kernel(
        const __hip_bfloat16* __restrict__ A,
        const __hip_bfloat16* __restrict__ Bt,
        int M, int K, int N,
        const float* __restrict__ bias,
        const float* __restrict__ sv, const float* __restrict__ tv,
        const float* resid, void* out) {
    __shared__ __align__(16) unsigned short SH[65536];    // 128 KB
    unsigned short* Asb = SH;            // [2][256*64]
    unsigned short* Bsb = SH + 32768;    // [2][256*64]
    int tid = threadIdx.x;
    // bijective XCD swizzle (m204): xcd = bid&7 ; lid = chunk_base(xcd) + bid/8
    int nwg = gridDim.x;
    int q8 = nwg >> 3, r8 = nwg & 7;
    int bid = blockIdx.x;
    int xcd = bid & 7;
    int lid = ((xcd < r8) ? xcd*(q8 + 1) : r8*(q8 + 1) + (xcd - r8)*q8) + (bid >> 3);
    int nx = N >> 8;
    int by = lid / nx;
    int bx = lid - by*nx;
    int nbase = bx << 8;
    int mbase = by << 8;
    int l = tid & 63, wv = tid >> 6;     // 8 waves
    int wm = wv & 1, wn = wv >> 1;       // wm 0..1 (128 rows), wn 0..3 (64 cols)
    int lm = l & 15, kq = l >> 4;
    f32x4 acc[8][4] = {};
    int nkt = K >> 6;

    auto stage = [&](int d, int kt) {
        int kb = kt << 6;
        #pragma unroll
        for (int i = 0; i < 4; i++) {
            int ch = i*512 + tid;            // 0..2047
            int row = ch >> 3;
            int sl = ch & 7;
            int kg = (sl ^ (row & 7)) << 3;  // swizzled source k-offset (elements)
            int am = mbase + row; if (am >= M) am = M - 1;
            const __hip_bfloat16* ga = A  + (size_t)am * K + kb + kg;
            const __hip_bfloat16* gb = Bt + (size_t)(nbase + row) * K + kb + kg;
            __builtin_amdgcn_global_load_lds(
                (const __attribute__((address_space(1))) void*)(unsigned long long)(uintptr_t)ga,
                (__attribute__((address_space(3))) void*)(unsigned long long)(uintptr_t)(Asb + d*16384 + ch*8),
                16, 0, 0);
            __builtin_amdgcn_global_load_lds(
                (const __attribute__((address_space(1))) void*)(unsigned long long)(uintptr_t)gb,
                (__attribute__((address_space(3))) void*)(unsigned long long)(uintptr_t)(Bsb + d*16384 + ch*8),
                16, 0, 0);
        }
    };

    stage(0, 0);
    __syncthreads();
    for (int kt = 0; kt < nkt; kt++) {
        if (kt + 1 < nkt) stage((kt + 1) & 1, kt + 1);   // prefetch next K-tile
        int d = kt & 1;
        const unsigned short* Ab = Asb + d*16384;
        const unsigned short* Bb = Bsb + d*16384;
        #pragma unroll
        for (int kk = 0; kk < 2; kk++) {
            bf16x8 af[8], bfv[4];
            #pragma unroll
            for (int i = 0; i < 8; i++) {
                int ra = wm*128 + i*16 + lm;
                af[i] = *(const bf16x8*)(Ab + ra*64 + ((((kk<<2)+kq) ^ (ra&7))<<3));
            }
            #pragma unroll
            for (int j = 0; j < 4; j++) {
                int rb = wn*64 + j*16 + lm;
                bfv[j] = *(const bf16x8*)(Bb + rb*64 + ((((kk<<2)+kq) ^ (rb&7))<<3));
            }
            #pragma unroll
            for (int i = 0; i < 8; i++)
                #pragma unroll
                for (int j = 0; j < 4; j++)
                    acc[i][j] = __builtin_amdgcn_mfma_f32_16x16x32_bf16(af[i], bfv[j], acc[i][j], 0, 0, 0);
        }
        __syncthreads();
    }

    int r0 = kq * 4;
    if (MODE == 0) {
        // epilogue: gelu+mod -> bf16 tile in LDS [256][256], then coalesced store
        #pragma unroll
        for (int j = 0; j < 4; j++) {
            int col = wn*64 + j*16 + lm;
            int gcol = nbase + col;
            float bb = bias[gcol];
            float ss = sv[gcol], tt = tv[gcol];
            #pragma unroll
            for (int i = 0; i < 8; i++) {
                int rowb = wm*128 + i*16 + r0;
                #pragma unroll
                for (int r = 0; r < 4; r++) {
                    float v = gelu_f((acc[i][j][r] + bb)*ss + tt);
                    __hip_bfloat16 hb = __float2bfloat16(v);
                    SH[(rowb + r)*256 + col] = *reinterpret_cast<unsigned short*>(&hb);
                }
            }
        }
        __syncthreads();
        #pragma unroll
        for (int it = 0; it < 16; it++) {
            int chunk = it*512 + tid;    // 8192 chunks of 16B (256 rows x 32)
            int row = chunk >> 5;
            int c8 = chunk & 31;
            int mr = mbase + row;
            if (mr < M) {
                *(u32x4*)((__hip_bfloat16*)out + (size_t)mr*N + nbase + c8*8) =
                    *(const u32x4*)(SH + row*256 + c8*8);
            }
        }
    } else {
        #pragma unroll
        for (int j = 0; j < 4; j++) {
            int col = nbase + wn*64 + j*16 + lm;
            float bb = bias[col];
            #pragma unroll
            for (int i = 0; i < 8; i++) {
                int rowb = mbase + wm*128 + i*16 + r0;
                #pragma unroll
                for (int r = 0; r < 4; r++) {
                    int row = rowb + r;
                    if (row < M) {
                        float v = acc[i][j][r] + bb;
                        ((float*)out)[(size_t)row*N + col] = v + resid[(size_t)row*N + col];
                    }
                }
            }
        }
    }
}

extern "C" void kernel_launch(void* const* d_in, const int* in_sizes, int n_in,
                              void* d_out, int out_size, void* d_ws, size_t ws_size,
                              hipStream_t stream) {
    const float* x     = (const float*)d_in[0];
    const float* emb   = (const float*)d_in[1];
    const float* n1w   = (const float*)d_in[2];
    const float* n1b   = (const float*)d_in[3];
    const float* n2w   = (const float*)d_in[4];
    const float* n2b   = (const float*)d_in[5];
    const float* w1    = (const float*)d_in[6];
    const float* b1    = (const float*)d_in[7];
    const float* w2    = (const float*)d_in[8];
    const float* b2    = (const float*)d_in[9];
    const float* fs_w0 = (const float*)d_in[10];
    const float* fs_b0 = (const float*)d_in[11];
    const float* fs_w1 = (const float*)d_in[12];
    const float* fs_b1 = (const float*)d_in[13];
    const float* fc1w  = (const float*)d_in[14];
    const float* fc1b  = (const float*)d_in[15];
    const float* fc2w  = (const float*)d_in[16];
    const float* fc2b  = (const float*)d_in[17];
    const float* ms_w0 = (const float*)d_in[18];
    const float* ms_b0 = (const float*)d_in[19];
    const float* ms_w1 = (const float*)d_in[20];
    const float* ms_b1 = (const float*)d_in[21];
    float* out = (float*)d_out;
    (void)in_sizes; (void)n_in; (void)out_size; (void)ws_size;

    char* wsb = (char*)d_ws;
    size_t off = 0;
    auto alloc = [&](size_t nbytes) -> void* {
        void* p = wsb + off;
        off += (nbytes + 255) & ~(size_t)255;
        return p;
    };
    float* s_f  = (float*)alloc(768*4);
    float* t_f  = (float*)alloc(768*4);
    float* s_m  = (float*)alloc(3072*4);
    float* t_m  = (float*)alloc(3072*4);
    float* midf = (float*)alloc(1536*4);
    float* midm = (float*)alloc(6144*4);
    __hip_bfloat16* Aw  = (__hip_bfloat16*)alloc((size_t)2*384*96*2);
    __hip_bfloat16* Ew  = (__hip_bfloat16*)alloc((size_t)192*384*2);
    __hip_bfloat16* Eh  = (__hip_bfloat16*)alloc((size_t)4*192*384*2);
    __hip_bfloat16* Bt1 = (__hip_bfloat16*)alloc((size_t)8*192*192*2);
    __hip_bfloat16* Bt2 = (__hip_bfloat16*)alloc((size_t)8*192*192*2);
    __hip_bfloat16* Yrb = (__hip_bfloat16*)alloc((size_t)NPOS*CC*2);
    __hip_bfloat16* Yib = (__hip_bfloat16*)alloc((size_t)NPOS*CC*2);
    __hip_bfloat16* Zrb = (__hip_bfloat16*)alloc((size_t)NPOS*CC*2);
    __hip_bfloat16* Zib = (__hip_bfloat16*)alloc((size_t)NPOS*CC*2);
    __hip_bfloat16* wT1  = (__hip_bfloat16*)alloc((size_t)CC*LAT*2);
    __hip_bfloat16* wT2  = (__hip_bfloat16*)alloc((size_t)CC*LAT*2);
    __hip_bfloat16* h2   = (__hip_bfloat16*)alloc((size_t)NROW*CC*2);
    __hip_bfloat16* hmid = (__hip_bfloat16*)alloc((size_t)NROW*LAT*2);
    // h_ln (bf16) aliases h2: lifetimes are disjoint
    __hip_bfloat16* hlnb = h2;

    // 1. modulation scale/shift vectors + twiddle/weight matrices
    mod_a_kernel<<<30, 256, 0, stream>>>(emb, fs_w0, fs_b0, ms_w0, ms_b0, midf, midm);
    mod_b_kernel<<<120, 512, 0, stream>>>(midf, midm, fs_w1, fs_b1, ms_w1, ms_b1,
                                          s_f, t_f, s_m, t_m);
    aw_kernel<<<144, 256, 0, stream>>>(Aw);
    ew_kernel<<<288, 256, 0, stream>>>(Ew);
    eh_kernel<<<1152, 256, 0, stream>>>(Eh);
    bdw_kernel<<<1152, 256, 0, stream>>>(w1, Bt1);
    bdw_kernel<<<1152, 256, 0, stream>>>(w2, Bt2);
    // 2. LN1 -> hlnb (bf16)
    ln_bf16_kernel<<<NROW/4, 256, 0, stream>>>(x, n1w, n1b, hlnb);
    // 3. weight convert+transpose
    transpose_bf16_kernel<<<dim3(LAT/32, CC/32), 256, 0, stream>>>(fc1w, wT1, 768, 3072);
    transpose_bf16_kernel<<<dim3(CC/32, LAT/32), 256, 0, stream>>>(fc2w, wT2, 3072, 768);

    // 4. filter path, all MFMA, bf16 intermediates
    transform_mfma<0><<<dim3(6, 1, 180), 256, 0, stream>>>(Ew, hlnb, nullptr, Yrb, Yib);
    transform_mfma<1><<<dim3(6, 2, 91), 256, 0, stream>>>(Eh, Yrb, Yib, Zrb, Zib);               // fwd
    bd_mfma_kernel<0><<<dim3(128, 8), 384, 0, stream>>>(Zrb, Zib, Bt1, b1, s_f, t_f, Yrb, Yib);
    bd_mfma_kernel<1><<<dim3(128, 8), 384, 0, stream>>>(Yrb, Yib, Bt2, b2, nullptr, nullptr, Zrb, Zib);
    transform_mfma<1><<<dim3(6, 2, 91), 256, 0, stream>>>(Eh + (size_t)2*192*384, Zrb, Zib, Yrb, Yib);  // inv
    iwdft_mfma_kernel<<<dim3(6, 3, 180), 256, 0, stream>>>(Yrb, Yib, Aw, hlnb, x, out);

    // 5. MLP path (d_out holds h; update in place)
    ln_bf16_kernel<<<NROW/4, 256, 0, stream>>>(out, n2w, n2b, h2);
    gemm256_kernel<0><<<dim3((LAT/256) * ((NROW+255)/256)), 512, 0, stream>>>(
        h2, wT1, NROW, CC, LAT, fc1b, s_m, t_m, nullptr, hmid);
    gemm256_kernel<1><<<dim3((CC/256) * ((NROW+255)/256)), 512, 0, stream>>>(
        hmid, wT2, NROW, LAT, CC, fc2b, nullptr, nullptr, out, out);
}

// Round 16
// 1875.428 us; speedup vs baseline: 2.1550x; 1.0138x over previous
//
#include <hip/hip_runtime.h>
#include <hip/hip_bf16.h>
#include <math.h>

// Problem constants
#define HH 180
#define WW 360
#define CC 768
#define FF 91          // kept W-frequencies (km = 91)
#define NPOS (HH*FF)   // 16380 frequency positions
#define NROW (HH*WW)   // 64800 spatial rows
#define LAT 3072

typedef __attribute__((ext_vector_type(8))) short bf16x8;
typedef __attribute__((ext_vector_type(4))) float f32x4;
typedef __attribute__((ext_vector_type(4))) unsigned int u32x4;

__device__ __forceinline__ float gelu_f(float x) {
    return 0.5f * x * (1.0f + erff(x * 0.7071067811865476f));
}

// ---------------- modulation stage A ----------------
__global__ __launch_bounds__(256) void mod_a_kernel(
        const float* __restrict__ e,
        const float* __restrict__ fs_w0, const float* __restrict__ fs_b0,
        const float* __restrict__ ms_w0, const float* __restrict__ ms_b0,
        float* __restrict__ mid_f, float* __restrict__ mid_m) {
    __shared__ float es[64];
    int t = threadIdx.x;
    if (t < 64) es[t] = e[t];
    __syncthreads();
    int j = blockIdx.x * 256 + t;
    if (j < 1536) {
        float a = fs_b0[j];
        #pragma unroll 8
        for (int k = 0; k < 64; k++) a += es[k] * fs_w0[k*1536 + j];
        mid_f[j] = gelu_f(a);
    } else {
        int jm = j - 1536;
        float a = ms_b0[jm];
        #pragma unroll 8
        for (int k = 0; k < 64; k++) a += es[k] * ms_w0[k*6144 + jm];
        mid_m[jm] = gelu_f(a);
    }
}

// ---------------- modulation stage B ----------------
__global__ __launch_bounds__(512) void mod_b_kernel(
        const float* __restrict__ mid_f, const float* __restrict__ mid_m,
        const float* __restrict__ fs_w1, const float* __restrict__ fs_b1,
        const float* __restrict__ ms_w1, const float* __restrict__ ms_b1,
        float* __restrict__ s_f, float* __restrict__ t_f,
        float* __restrict__ s_m, float* __restrict__ t_m) {
    __shared__ float red[8*64];
    int t = threadIdx.x;
    int g = t >> 6;
    int jl = t & 63;
    int blk = blockIdx.x;
    if (blk < 24) {
        int jo = blk*64 + jl;
        const int N = 1536, NQ = 192;
        float a = 0.f;
        const float* w = fs_w1 + (size_t)(g*NQ)*N + jo;
        for (int j = 0; j < NQ; j++) a += mid_f[g*NQ + j] * w[(size_t)j*N];
        red[t] = a;
        __syncthreads();
        if (t < 64) {
            float s = fs_b1[jo];
            #pragma unroll
            for (int q = 0; q < 8; q++) s += red[q*64 + jl];
            if (jo < 768) s_f[jo] = 1.0f + s;
            else          t_f[jo - 768] = s;
        }
    } else {
        int jo = (blk - 24)*64 + jl;
        const int N = 6144, NQ = 768;
        float a = 0.f;
        const float* w = ms_w1 + (size_t)(g*NQ)*N + jo;
        for (int j = 0; j < NQ; j++) a += mid_m[g*NQ + j] * w[(size_t)j*N];
        red[t] = a;
        __syncthreads();
        if (t < 64) {
            float s = ms_b1[jo];
            #pragma unroll
            for (int q = 0; q < 8; q++) s += red[q*64 + jl];
            if (jo < 3072) s_m[jo] = 1.0f + s;
            else           t_m[jo - 3072] = s;
        }
    }
}

// ---------------- LayerNorm bf16 out ----------------
__global__ __launch_bounds__(256) void ln_bf16_kernel(const float* __restrict__ in,
        const float* __restrict__ w, const float* __restrict__ b,
        __hip_bfloat16* __restrict__ out) {
    int row = blockIdx.x*4 + (threadIdx.x >> 6);
    int l = threadIdx.x & 63;
    const float* p = in + (size_t)row*CC;
    float v[12]; float s = 0.f, sq = 0.f;
    #pragma unroll
    for (int i = 0; i < 12; i++) { float tv = p[l + 64*i]; v[i] = tv; s += tv; sq += tv*tv; }
    #pragma unroll
    for (int m = 1; m < 64; m <<= 1) { s += __shfl_xor(s, m); sq += __shfl_xor(sq, m); }
    float mean = s * (1.0f/768.0f);
    float var  = sq * (1.0f/768.0f) - mean*mean;
    float rstd = rsqrtf(var + 1e-5f);
    __hip_bfloat16* o = out + (size_t)row*CC;
    #pragma unroll
    for (int i = 0; i < 12; i++) { int c = l + 64*i; o[c] = __float2bfloat16((v[i]-mean)*rstd*w[c] + b[c]); }
}

// ---------------- twiddle matrices ----------------
__global__ __launch_bounds__(256) void ew_kernel(__hip_bfloat16* __restrict__ Ew) {
    int idx = blockIdx.x*256 + threadIdx.x;
    if (idx >= 192*384) return;
    int r = idx / 384, w = idx - (idx/384)*384;
    int f = (r < 96) ? r : r - 96;
    const float rn = 0.05270462766947299f;  // 1/sqrt(360)
    float v = 0.f;
    if (f < FF && w < WW) {
        int p = (f * w) % 360;
        float ang = 6.283185307179586f/360.0f * (float)p;
        float s_, c_; sincosf(ang, &s_, &c_);
        v = (r < 96) ? c_*rn : -s_*rn;
    }
    Ew[idx] = __float2bfloat16(v);
}

__global__ __launch_bounds__(256) void eh_kernel(__hip_bfloat16* __restrict__ Eh) {
    int idx = blockIdx.x*256 + threadIdx.x;
    if (idx >= 4*192*384) return;
    int sp = idx / (192*384);
    int rem = idx - sp*(192*384);
    int t = rem / 384, k = rem - (rem/384)*384;
    int sig = sp >> 1, plane = sp & 1;
    float s = (sig == 0) ? -1.f : 1.f;
    int h = (k < 192) ? k : k - 192;
    const float rnh = 0.07453559924999299f;  // 1/sqrt(180)
    float v = 0.f;
    if (t < HH && h < HH) {
        int p = (t * h) % 180;
        float ang = 6.283185307179586f/180.0f * (float)p;
        float s_, c_; sincosf(ang, &s_, &c_);
        float C = c_*rnh, S = s_*rnh;
        if (plane == 0) v = (k < 192) ? C : -s*S;
        else            v = (k < 192) ? s*S : C;
    }
    Eh[idx] = __float2bfloat16(v);
}

// ---------------- bd stacked-complex weight pack ----------------
__global__ __launch_bounds__(256) void bdw_kernel(const float* __restrict__ w,
        __hip_bfloat16* __restrict__ Bt) {
    int idx = blockIdx.x*256 + threadIdx.x;   // 8*192*192 = 294912
    if (idx >= 8*192*192) return;
    int wb = idx / (192*192);
    int rem = idx - wb*(192*192);
    int n2 = rem / 192, k2 = rem - (rem/192)*192;
    int k = (k2 < 96) ? k2 : k2 - 96;
    int oc = (n2 < 96) ? n2 : n2 - 96;
    float w0 = w[((size_t)wb*96 + k)*96 + oc];
    float w1v = w[((size_t)(8 + wb)*96 + k)*96 + oc];
    float v;
    if (n2 < 96) v = (k2 < 96) ? w0 : -w1v;
    else         v = (k2 < 96) ? w1v : w0;
    Bt[idx] = __float2bfloat16(v);
}

// ---------------- MFMA transform: C[192 rows][128 c] = A[192][384] @ B[384][c], all bf16 I/O ----------------
// staging address math hoisted out of the K-loop (only kb advances)
template<int MODE>
__global__ __launch_bounds__(256) void transform_mfma(
        const __hip_bfloat16* __restrict__ Amat,
        const __hip_bfloat16* __restrict__ B0, const __hip_bfloat16* __restrict__ B1,
        __hip_bfloat16* __restrict__ O0, __hip_bfloat16* __restrict__ O1) {
    __shared__ __align__(16) unsigned short As[192*72];
    __shared__ __align__(16) unsigned short Bs[128*72];
    int nbase = blockIdx.x * 128;
    int bat = blockIdx.z;
    int tid = threadIdx.x;
    int l = tid & 63, wv = tid >> 6;
    int wm = wv & 1, wn = wv >> 1;
    int lm = l & 15, kq = l >> 4;
    const __hip_bfloat16* Ab = Amat + (MODE == 1 ? (size_t)blockIdx.y*192*384 : 0);
    // hoisted A-staging bases (6 chunks): row/co fixed, advance kb
    const __hip_bfloat16* pa[6];
    unsigned short* dsa[6];
    #pragma unroll
    for (int it = 0; it < 6; it++) {
        int ch = it*256 + tid;
        int row = ch >> 3, co = (ch & 7) * 8;
        pa[it]  = Ab + (size_t)row*384 + co;
        dsa[it] = As + row*72 + co;
    }
    // hoisted B-staging bases (4 chunks): row (k-local), cq fixed
    const __hip_bfloat16* pb[4];
    int  brow[4];
    unsigned short* dsb[4];
    #pragma unroll
    for (int it = 0; it < 4; it++) {
        int idx = it*256 + tid;
        int row = idx >> 4;
        int cq = (idx & 15) * 8;
        brow[it] = row;
        dsb[it] = Bs + (size_t)cq*72 + row;   // writes at dsb + (2j)*72 / (2j+1)*72
        if (MODE == 0) {
            pb[it] = B0 + (size_t)bat*WW*CC + (size_t)row*CC + nbase + cq;
        } else {
            pb[it] = nullptr;
        }
    }
    f32x4 acc[6][4] = {};
    for (int kt = 0; kt < 6; kt++) {
        int kb = kt*64;
        __syncthreads();
        #pragma unroll
        for (int it = 0; it < 6; it++) {
            u32x4 v = *(const u32x4*)(pa[it] + kb);
            *(u32x4*)(dsa[it]) = v;
        }
        #pragma unroll
        for (int it = 0; it < 4; it++) {
            int row = brow[it];
            int k = kb + row;
            unsigned int u[4] = {0u, 0u, 0u, 0u};
            if (MODE == 0) {
                if (k < WW) {
                    u32x4 v = *(const u32x4*)(pb[it] + (size_t)kb*CC);
                    u[0] = v[0]; u[1] = v[1]; u[2] = v[2]; u[3] = v[3];
                }
            } else {
                int idx = it*256 + tid;
                int cq = (idx & 15) * 8;
                if (k < 192) {
                    if (k < HH) {
                        u32x4 v = *(const u32x4*)(B0 + (size_t)k*FF*CC + (size_t)bat*CC + nbase + cq);
                        u[0] = v[0]; u[1] = v[1]; u[2] = v[2]; u[3] = v[3];
                    }
                } else {
                    int h2 = k - 192;
                    if (h2 < HH) {
                        u32x4 v = *(const u32x4*)(B1 + (size_t)h2*FF*CC + (size_t)bat*CC + nbase + cq);
                        u[0] = v[0]; u[1] = v[1]; u[2] = v[2]; u[3] = v[3];
                    }
                }
            }
            unsigned short* db = dsb[it];
            #pragma unroll
            for (int j = 0; j < 4; j++) {
                db[(2*j    )*72] = (unsigned short)(u[j] & 0xffffu);
                db[(2*j + 1)*72] = (unsigned short)(u[j] >> 16);
            }
        }
        __syncthreads();
        #pragma unroll
        for (int kk = 0; kk < 2; kk++) {
            int kg = kk*32 + kq*8;
            bf16x8 af[6], bfv[4];
            #pragma unroll
            for (int i = 0; i < 6; i++)
                af[i] = *(const bf16x8*)(As + (wm*96 + i*16 + lm)*72 + kg);
            #pragma unroll
            for (int j = 0; j < 4; j++)
                bfv[j] = *(const bf16x8*)(Bs + (wn*64 + j*16 + lm)*72 + kg);
            #pragma unroll
            for (int i = 0; i < 6; i++)
                #pragma unroll
                for (int j = 0; j < 4; j++)
                    acc[i][j] = __builtin_amdgcn_mfma_f32_16x16x32_bf16(af[i], bfv[j], acc[i][j], 0, 0, 0);
        }
    }
    int r0 = kq * 4;
    #pragma unroll
    for (int j = 0; j < 4; j++) {
        int col = nbase + wn*64 + j*16 + lm;
        #pragma unroll
        for (int i = 0; i < 6; i++) {
            #pragma unroll
            for (int r = 0; r < 4; r++) {
                int row = wm*96 + i*16 + r0 + r;
                __hip_bfloat16 hv = __float2bfloat16(acc[i][j][r]);
                if (MODE == 0) {
                    if (row < 96) {
                        if (row < FF) O0[(size_t)bat*FF*CC + (size_t)row*CC + col] = hv;
                    } else {
                        int f2 = row - 96;
                        if (f2 < FF) O1[(size_t)bat*FF*CC + (size_t)f2*CC + col] = hv;
                    }
                } else {
                    if (row < HH) {
                        __hip_bfloat16* Op = blockIdx.y ? O1 : O0;
                        Op[(size_t)row*FF*CC + (size_t)bat*CC + col] = hv;
                    }
                }
            }
        }
    }
}

// ---------------- block-diagonal complex matmul via MFMA (stacked-complex GEMM), bf16 I/O ----------------
template<int LAYER>
__global__ __launch_bounds__(384) void bd_mfma_kernel(
        const __hip_bfloat16* __restrict__ Ir, const __hip_bfloat16* __restrict__ Ii,
        const __hip_bfloat16* __restrict__ Bt,
        const float* __restrict__ bias,
        const float* __restrict__ sf, const float* __restrict__ tf,
        __hip_bfloat16* __restrict__ Or_, __hip_bfloat16* __restrict__ Oi_) {
    __shared__ __align__(16) unsigned short As[128*72];
    __shared__ __align__(16) unsigned short Bs[192*72];
    int mbase = blockIdx.x * 128;
    int wb = blockIdx.y;
    int tid = threadIdx.x;
    int l = tid & 63, wv = tid >> 6;      // 6 waves
    int wm = wv & 1, wn = wv >> 1;
    int lm = l & 15, kq = l >> 4;
    const __hip_bfloat16* Bw = Bt + (size_t)wb*192*192;
    f32x4 acc[4][4] = {};
    for (int kt = 0; kt < 3; kt++) {
        __syncthreads();
        for (int ch = tid; ch < 1024; ch += 384) {
            int row = ch >> 3, q = ch & 7;
            int k2 = kt*64 + q*8;
            int p = mbase + row; if (p >= NPOS) p = NPOS - 1;
            const __hip_bfloat16* src = (k2 < 96) ? (Ir + (size_t)p*CC + wb*96 + k2)
                                                  : (Ii + (size_t)p*CC + wb*96 + (k2 - 96));
            *(u32x4*)(As + row*72 + q*8) = *(const u32x4*)src;
        }
        for (int ch = tid; ch < 1536; ch += 384) {
            int row = ch >> 3, co = (ch & 7) * 8;
            u32x4 v = *(const u32x4*)(Bw + (size_t)row*192 + kt*64 + co);
            *(u32x4*)(Bs + row*72 + co) = v;
        }
        __syncthreads();
        #pragma unroll
        for (int kk = 0; kk < 2; kk++) {
            int kg = kk*32 + kq*8;
            bf16x8 af[4], bfv[4];
            #pragma unroll
            for (int i = 0; i < 4; i++) {
                af[i]  = *(const bf16x8*)(As + (wm*64 + i*16 + lm)*72 + kg);
                bfv[i] = *(const bf16x8*)(Bs + (wn*64 + i*16 + lm)*72 + kg);
            }
            #pragma unroll
            for (int i = 0; i < 4; i++)
                #pragma unroll
                for (int j = 0; j < 4; j++)
                    acc[i][j] = __builtin_amdgcn_mfma_f32_16x16x32_bf16(af[i], bfv[j], acc[i][j], 0, 0, 0);
        }
    }
    int r0 = kq * 4;
    #pragma unroll
    for (int j = 0; j < 4; j++) {
        int n2 = wn*64 + j*16 + lm;
        int oc = (n2 < 96) ? n2 : n2 - 96;
        float bb = bias[((n2 < 96) ? 0 : 768) + wb*96 + oc];
        float ss = 0.f, tt = 0.f;
        if (LAYER == 0) { ss = sf[wb*96 + oc]; tt = tf[wb*96 + oc]; }
        __hip_bfloat16* Op = (n2 < 96) ? Or_ : Oi_;
        #pragma unroll
        for (int i = 0; i < 4; i++) {
            #pragma unroll
            for (int r = 0; r < 4; r++) {
                int p = mbase + wm*64 + i*16 + r0 + r;
                if (p < NPOS) {
                    float v = acc[i][j][r] + bb;
                    if (LAYER == 0) {
                        v = fmaxf(v*ss + tt, 0.0f);
                    } else {
                        v = (v > 0.01f) ? (v - 0.01f) : ((v < -0.01f) ? (v + 0.01f) : 0.0f);
                    }
                    Op[(size_t)p*CC + wb*96 + oc] = __float2bfloat16(v);
                }
            }
        }
    }
}

// ---------------- inverse W-DFT matrices (bf16) ----------------
__global__ __launch_bounds__(256) void aw_kernel(__hip_bfloat16* __restrict__ Aw) {
    int idx = blockIdx.x*256 + threadIdx.x;   // 384*96 = 36864
    if (idx >= 384*96) return;
    int w = idx / 96, f = idx - (idx/96)*96;
    const float rn = 0.05270462766947299f;
    float m = (f == 0) ? rn : ((f < FF) ? 2.0f*rn : 0.0f);
    int p = (int)(((long long)f * w) % 360);
    float ang = 6.283185307179586f / 360.0f * (float)p;
    float s_, c_; sincosf(ang, &s_, &c_);
    Aw[idx]          = __float2bfloat16(m * c_);
    Aw[384*96 + idx] = __float2bfloat16(-m * s_);
}

// ---------------- inverse rDFT along W via MFMA; out = idft + hln(bf16) + x ----------------
__global__ __launch_bounds__(256) void iwdft_mfma_kernel(
        const __hip_bfloat16* __restrict__ Zr, const __hip_bfloat16* __restrict__ Zi,
        const __hip_bfloat16* __restrict__ Aw,
        const __hip_bfloat16* __restrict__ hlnb,
        const float* __restrict__ xin, float* __restrict__ hout) {
    __shared__ __align__(16) unsigned short As[128*104];
    __shared__ __align__(16) unsigned short Bs[128*104];
    int h = blockIdx.z;
    int mbase = blockIdx.y * 128;   // w
    int nbase = blockIdx.x * 128;   // c
    int tid = threadIdx.x;
    int l = tid & 63, wv = tid >> 6;
    int wm = wv & 1, wn = wv >> 1;
    int lm = l & 15, kq = l >> 4;
    f32x4 acc[4][4] = {};
    #pragma unroll
    for (int ph = 0; ph < 2; ph++) {
        __syncthreads();
        for (int ch = tid; ch < 1536; ch += 256) {
            int row = ch / 12, co = (ch - row*12) * 8;
            u32x4 v = *(const u32x4*)(Aw + ((size_t)ph*384 + mbase + row)*96 + co);
            *(u32x4*)(As + row*104 + co) = v;
        }
        const __hip_bfloat16* Zp = ph ? Zi : Zr;
        for (int ch = tid; ch < 1536; ch += 256) {   // 96 f x 16 groups of 8 c
            int f = ch >> 4, cq = (ch & 15) * 8;
            unsigned int u[4] = {0u, 0u, 0u, 0u};
            if (f < FF) {
                u32x4 v = *(const u32x4*)(Zp + ((size_t)h*FF + f)*CC + nbase + cq);
                u[0] = v[0]; u[1] = v[1]; u[2] = v[2]; u[3] = v[3];
            }
            #pragma unroll
            for (int j = 0; j < 4; j++) {
                Bs[(cq + 2*j    )*104 + f] = (unsigned short)(u[j] & 0xffffu);
                Bs[(cq + 2*j + 1)*104 + f] = (unsigned short)(u[j] >> 16);
            }
        }
        __syncthreads();
        #pragma unroll
        for (int ks = 0; ks < 3; ks++) {
            int kg = ks*32 + kq*8;
            bf16x8 af[4], bfv[4];
            #pragma unroll
            for (int i = 0; i < 4; i++) {
                af[i]  = *(const bf16x8*)(As + (wm*64 + i*16 + lm)*104 + kg);
                bfv[i] = *(const bf16x8*)(Bs + (wn*64 + i*16 + lm)*104 + kg);
            }
            #pragma unroll
            for (int i = 0; i < 4; i++)
                #pragma unroll
                for (int j = 0; j < 4; j++)
                    acc[i][j] = __builtin_amdgcn_mfma_f32_16x16x32_bf16(af[i], bfv[j], acc[i][j], 0, 0, 0);
        }
    }
    int r0 = kq * 4;
    #pragma unroll
    for (int j = 0; j < 4; j++) {
        int col = nbase + wn*64 + j*16 + lm;
        #pragma unroll
        for (int i = 0; i < 4; i++) {
            int rowb = wm*64 + i*16 + r0;
            #pragma unroll
            for (int r = 0; r < 4; r++) {
                int wp = mbase + rowb + r;
                if (wp < WW) {
                    size_t idx = ((size_t)h*WW + wp)*CC + col;
                    hout[idx] = acc[i][j][r] + __bfloat162float(hlnb[idx]) + xin[idx];
                }
            }
        }
    }
}

// ---------------- tiled weight transpose + bf16 convert ----------------
__global__ __launch_bounds__(256) void transpose_bf16_kernel(const float* __restrict__ src,
        __hip_bfloat16* __restrict__ dst, int K, int N) {
    __shared__ float tile[32][33];
    int n0 = blockIdx.x * 32;
    int k0 = blockIdx.y * 32;
    int tx = threadIdx.x & 31;
    int ty = threadIdx.x >> 5;
    #pragma unroll
    for (int r = 0; r < 32; r += 8) {
        tile[ty + r][tx] = src[(size_t)(k0 + ty + r) * N + n0 + tx];
    }
    __syncthreads();
    #pragma unroll
    for (int r = 0; r < 32; r += 8) {
        dst[(size_t)(n0 + ty + r) * K + k0 + tx] = __float2bfloat16(tile[tx][ty + r]);
    }
}

// ---------------- bf16 MFMA GEMM, 256x256 tile, BK=64, 8 waves (2M x 4N), 2-phase dbuf ----------------
// 1D grid + bijective XCD-chunked swizzle (T1/m204); XOR-swizzle slot = kchunk ^ (row&7)
// staging address math hoisted out of the K-loop (8 base pointers, advance kt<<6)
// MODE 0: out = bf16(gelu((A@B + bias)*s + t)), LDS-staged coalesced store
// MODE 1: out = A@B + bias + resid (fp32)
template<int MODE>
__global__ __launch_bounds__(512, 2) void gemm256_kernel(
        const __hip_bfloat16* __restrict__ A,
        const __hip_bfloat16* __restrict__ Bt,
        int M, int K, int N,
        const float* __restrict__ bias,
        const float* __restrict__ sv, const float* __restrict__ tv,
        const float* resid, void* out) {
    __shared__ __align__(16) unsigned short SH[65536];    // 128 KB
    unsigned short* Asb = SH;            // [2][256*64]
    unsigned short* Bsb = SH + 32768;    // [2][256*64]
    int tid = threadIdx.x;
    // bijective XCD swizzle (m204)
    int nwg = gridDim.x;
    int q8 = nwg >> 3, r8 = nwg & 7;
    int bid = blockIdx.x;
    int xcd = bid & 7;
    int lid = ((xcd < r8) ? xcd*(q8 + 1) : r8*(q8 + 1) + (xcd - r8)*q8) + (bid >> 3);
    int nx = N >> 8;
    int by = lid / nx;
    int bx = lid - by*nx;
    int nbase = bx << 8;
    int mbase = by << 8;
    int l = tid & 63, wv = tid >> 6;     // 8 waves
    int wm = wv & 1, wn = wv >> 1;       // wm 0..1 (128 rows), wn 0..3 (64 cols)
    int lm = l & 15, kq = l >> 4;
    f32x4 acc[8][4] = {};
    int nkt = K >> 6;

    // hoisted staging bases: 4 chunks x (A,B); row/sl/kg/clamp are kt-invariant
    const __hip_bfloat16* pga[4];
    const __hip_bfloat16* pgb[4];
    int ldso[4];                         // LDS short-offset for chunk (d adds 16384)
    #pragma unroll
    for (int i = 0; i < 4; i++) {
        int ch = i*512 + tid;            // 0..2047
        int row = ch >> 3;
        int sl = ch & 7;
        int kg = (sl ^ (row & 7)) << 3;
        int am = mbase + row; if (am >= M) am = M - 1;
        pga[i] = A  + (size_t)am * K + kg;
        pgb[i] = Bt + (size_t)(nbase + row) * K + kg;
        ldso[i] = ch*8;
    }
    auto stage = [&](int d, int kt) {
        int kb = kt << 6;
        int db = d*16384;
        #pragma unroll
        for (int i = 0; i < 4; i++) {
            __builtin_amdgcn_global_load_lds(
                (const __attribute__((address_space(1))) void*)(unsigned long long)(uintptr_t)(pga[i] + kb),
                (__attribute__((address_space(3))) void*)(unsigned long long)(uintptr_t)(Asb + db + ldso[i]),
                16, 0, 0);
            __builtin_amdgcn_global_load_lds(
                (const __attribute__((address_space(1))) void*)(unsigned long long)(uintptr_t)(pgb[i] + kb),
                (__attribute__((address_space(3))) void*)(unsigned long long)(uintptr_t)(Bsb + db + ldso[i]),
                16, 0, 0);
        }
    };

    stage(0, 0);
    __syncthreads();
    for (int kt = 0; kt < nkt; kt++) {
        if (kt + 1 < nkt) stage((kt + 1) & 1, kt + 1);   // prefetch next K-tile
        int d = kt & 1;
        const unsigned short* Ab = Asb + d*16384;
        const unsigned short* Bb = Bsb + d*16384;
        #pragma unroll
        for (int kk = 0; kk < 2; kk++) {
            bf16x8 af[8], bfv[4];
            #pragma unroll
            for (int i = 0; i < 8; i++) {
                int ra = wm*128 + i*16 + lm;
                af[i] = *(const bf16x8*)(Ab + ra*64 + ((((kk<<2)+kq) ^ (ra&7))<<3));
            }
            #pragma unroll
            for (int j = 0; j < 4; j++) {
                int rb = wn*64 + j*16 + lm;
                bfv[j] = *(const bf16x8*)(Bb + rb*64 + ((((kk<<2)+kq) ^ (rb&7))<<3));
            }
            #pragma unroll
            for (int i = 0; i < 8; i++)
                #pragma unroll
                for (int j = 0; j < 4; j++)
                    acc[i][j] = __builtin_amdgcn_mfma_f32_16x16x32_bf16(af[i], bfv[j], acc[i][j], 0, 0, 0);
        }
        __syncthreads();
    }

    int r0 = kq * 4;
    if (MODE == 0) {
        // epilogue: gelu+mod -> bf16 tile in LDS [256][256], then coalesced store
        #pragma unroll
        for (int j = 0; j < 4; j++) {
            int col = wn*64 + j*16 + lm;
            int gcol = nbase + col;
            float bb = bias[gcol];
            float ss = sv[gcol], tt = tv[gcol];
            #pragma unroll
            for (int i = 0; i < 8; i++) {
                int rowb = wm*128 + i*16 + r0;
                #pragma unroll
                for (int r = 0; r < 4; r++) {
                    float v = gelu_f((acc[i][j][r] + bb)*ss + tt);
                    __hip_bfloat16 hb = __float2bfloat16(v);
                    SH[(rowb + r)*256 + col] = *reinterpret_cast<unsigned short*>(&hb);
                }
            }
        }
        __syncthreads();
        #pragma unroll
        for (int it = 0; it < 16; it++) {
            int chunk = it*512 + tid;    // 8192 chunks of 16B (256 rows x 32)
            int row = chunk >> 5;
            int c8 = chunk & 31;
            int mr = mbase + row;
            if (mr < M) {
                *(u32x4*)((__hip_bfloat16*)out + (size_t)mr*N + nbase + c8*8) =
                    *(const u32x4*)(SH + row*256 + c8*8);
            }
        }
    } else {
        #pragma unroll
        for (int j = 0; j < 4; j++) {
            int col = nbase + wn*64 + j*16 + lm;
            float bb = bias[col];
            #pragma unroll
            for (int i = 0; i < 8; i++) {
                int rowb = mbase + wm*128 + i*16 + r0;
                #pragma unroll
                for (int r = 0; r < 4; r++) {
                    int row = rowb + r;
                    if (row < M) {
                        float v = acc[i][j][r] + bb;
                        ((float*)out)[(size_t)row*N + col] = v + resid[(size_t)row*N + col];
                    }
                }
            }
        }
    }
}

extern "C" void kernel_launch(void* const* d_in, const int* in_sizes, int n_in,
                              void* d_out, int out_size, void* d_ws, size_t ws_size,
                              hipStream_t stream) {
    const float* x     = (const float*)d_in[0];
    const float* emb   = (const float*)d_in[1];
    const float* n1w   = (const float*)d_in[2];
    const float* n1b   = (const float*)d_in[3];
    const float* n2w   = (const float*)d_in[4];
    const float* n2b   = (const float*)d_in[5];
    const float* w1    = (const float*)d_in[6];
    const float* b1    = (const float*)d_in[7];
    const float* w2    = (const float*)d_in[8];
    const float* b2    = (const float*)d_in[9];
    const float* fs_w0 = (const float*)d_in[10];
    const float* fs_b0 = (const float*)d_in[11];
    const float* fs_w1 = (const float*)d_in[12];
    const float* fs_b1 = (const float*)d_in[13];
    const float* fc1w  = (const float*)d_in[14];
    const float* fc1b  = (const float*)d_in[15];
    const float* fc2w  = (const float*)d_in[16];
    const float* fc2b  = (const float*)d_in[17];
    const float* ms_w0 = (const float*)d_in[18];
    const float* ms_b0 = (const float*)d_in[19];
    const float* ms_w1 = (const float*)d_in[20];
    const float* ms_b1 = (const float*)d_in[21];
    float* out = (float*)d_out;
    (void)in_sizes; (void)n_in; (void)out_size; (void)ws_size;

    char* wsb = (char*)d_ws;
    size_t off = 0;
    auto alloc = [&](size_t nbytes) -> void* {
        void* p = wsb + off;
        off += (nbytes + 255) & ~(size_t)255;
        return p;
    };
    float* s_f  = (float*)alloc(768*4);
    float* t_f  = (float*)alloc(768*4);
    float* s_m  = (float*)alloc(3072*4);
    float* t_m  = (float*)alloc(3072*4);
    float* midf = (float*)alloc(1536*4);
    float* midm = (float*)alloc(6144*4);
    __hip_bfloat16* Aw  = (__hip_bfloat16*)alloc((size_t)2*384*96*2);
    __hip_bfloat16* Ew  = (__hip_bfloat16*)alloc((size_t)192*384*2);
    __hip_bfloat16* Eh  = (__hip_bfloat16*)alloc((size_t)4*192*384*2);
    __hip_bfloat16* Bt1 = (__hip_bfloat16*)alloc((size_t)8*192*192*2);
    __hip_bfloat16* Bt2 = (__hip_bfloat16*)alloc((size_t)8*192*192*2);
    __hip_bfloat16* Yrb = (__hip_bfloat16*)alloc((size_t)NPOS*CC*2);
    __hip_bfloat16* Yib = (__hip_bfloat16*)alloc((size_t)NPOS*CC*2);
    __hip_bfloat16* Zrb = (__hip_bfloat16*)alloc((size_t)NPOS*CC*2);
    __hip_bfloat16* Zib = (__hip_bfloat16*)alloc((size_t)NPOS*CC*2);
    __hip_bfloat16* wT1  = (__hip_bfloat16*)alloc((size_t)CC*LAT*2);
    __hip_bfloat16* wT2  = (__hip_bfloat16*)alloc((size_t)CC*LAT*2);
    __hip_bfloat16* h2   = (__hip_bfloat16*)alloc((size_t)NROW*CC*2);
    __hip_bfloat16* hmid = (__hip_bfloat16*)alloc((size_t)NROW*LAT*2);
    // h_ln (bf16) aliases h2: lifetimes are disjoint
    __hip_bfloat16* hlnb = h2;

    // 1. modulation scale/shift vectors + twiddle/weight matrices
    mod_a_kernel<<<30, 256, 0, stream>>>(emb, fs_w0, fs_b0, ms_w0, ms_b0, midf, midm);
    mod_b_kernel<<<120, 512, 0, stream>>>(midf, midm, fs_w1, fs_b1, ms_w1, ms_b1,
                                          s_f, t_f, s_m, t_m);
    aw_kernel<<<144, 256, 0, stream>>>(Aw);
    ew_kernel<<<288, 256, 0, stream>>>(Ew);
    eh_kernel<<<1152, 256, 0, stream>>>(Eh);
    bdw_kernel<<<1152, 256, 0, stream>>>(w1, Bt1);
    bdw_kernel<<<1152, 256, 0, stream>>>(w2, Bt2);
    // 2. LN1 -> hlnb (bf16)
    ln_bf16_kernel<<<NROW/4, 256, 0, stream>>>(x, n1w, n1b, hlnb);
    // 3. weight convert+transpose
    transpose_bf16_kernel<<<dim3(LAT/32, CC/32), 256, 0, stream>>>(fc1w, wT1, 768, 3072);
    transpose_bf16_kernel<<<dim3(CC/32, LAT/32), 256, 0, stream>>>(fc2w, wT2, 3072, 768);

    // 4. filter path, all MFMA, bf16 intermediates
    transform_mfma<0><<<dim3(6, 1, 180), 256, 0, stream>>>(Ew, hlnb, nullptr, Yrb, Yib);
    transform_mfma<1><<<dim3(6, 2, 91), 256, 0, stream>>>(Eh, Yrb, Yib, Zrb, Zib);               // fwd
    bd_mfma_kernel<0><<<dim3(128, 8), 384, 0, stream>>>(Zrb, Zib, Bt1, b1, s_f, t_f, Yrb, Yib);
    bd_mfma_kernel<1><<<dim3(128, 8), 384, 0, stream>>>(Yrb, Yib, Bt2, b2, nullptr, nullptr, Zrb, Zib);
    transform_mfma<1><<<dim3(6, 2, 91), 256, 0, stream>>>(Eh + (size_t)2*192*384, Zrb, Zib, Yrb, Yib);  // inv
    iwdft_mfma_kernel<<<dim3(6, 3, 180), 256, 0, stream>>>(Yrb, Yib, Aw, hlnb, x, out);

    // 5. MLP path (d_out holds h; update in place)
    ln_bf16_kernel<<<NROW/4, 256, 0, stream>>>(out, n2w, n2b, h2);
    gemm256_kernel<0><<<dim3((LAT/256) * ((NROW+255)/256)), 512, 0, stream>>>(
        h2, wT1, NROW, CC, LAT, fc1b, s_m, t_m, nullptr, hmid);
    gemm256_kernel<1><<<dim3((CC/256) * ((NROW+255)/256)), 512, 0, stream>>>(
        hmid, wT2, NROW, LAT, CC, fc2b, nullptr, nullptr, out, out);
}

// Round 17
// 1838.028 us; speedup vs baseline: 2.1988x; 1.0203x over previous
//
#include <hip/hip_runtime.h>
#include <hip/hip_bf16.h>
#include <math.h>

// Problem constants
#define HH 180
#define WW 360
#define CC 768
#define FF 91          // kept W-frequencies (km = 91)
#define NPOS (HH*FF)   // 16380 frequency positions
#define NROW (HH*WW)   // 64800 spatial rows
#define LAT 3072

typedef __attribute__((ext_vector_type(8))) short bf16x8;
typedef __attribute__((ext_vector_type(4))) float f32x4;
typedef __attribute__((ext_vector_type(4))) unsigned int u32x4;

__device__ __forceinline__ float gelu_f(float x) {
    return 0.5f * x * (1.0f + erff(x * 0.7071067811865476f));
}

// ---------------- modulation stage A ----------------
__global__ __launch_bounds__(256) void mod_a_kernel(
        const float* __restrict__ e,
        const float* __restrict__ fs_w0, const float* __restrict__ fs_b0,
        const float* __restrict__ ms_w0, const float* __restrict__ ms_b0,
        float* __restrict__ mid_f, float* __restrict__ mid_m) {
    __shared__ float es[64];
    int t = threadIdx.x;
    if (t < 64) es[t] = e[t];
    __syncthreads();
    int j = blockIdx.x * 256 + t;
    if (j < 1536) {
        float a = fs_b0[j];
        #pragma unroll 8
        for (int k = 0; k < 64; k++) a += es[k] * fs_w0[k*1536 + j];
        mid_f[j] = gelu_f(a);
    } else {
        int jm = j - 1536;
        float a = ms_b0[jm];
        #pragma unroll 8
        for (int k = 0; k < 64; k++) a += es[k] * ms_w0[k*6144 + jm];
        mid_m[jm] = gelu_f(a);
    }
}

// ---------------- modulation stage B ----------------
__global__ __launch_bounds__(512) void mod_b_kernel(
        const float* __restrict__ mid_f, const float* __restrict__ mid_m,
        const float* __restrict__ fs_w1, const float* __restrict__ fs_b1,
        const float* __restrict__ ms_w1, const float* __restrict__ ms_b1,
        float* __restrict__ s_f, float* __restrict__ t_f,
        float* __restrict__ s_m, float* __restrict__ t_m) {
    __shared__ float red[8*64];
    int t = threadIdx.x;
    int g = t >> 6;
    int jl = t & 63;
    int blk = blockIdx.x;
    if (blk < 24) {
        int jo = blk*64 + jl;
        const int N = 1536, NQ = 192;
        float a = 0.f;
        const float* w = fs_w1 + (size_t)(g*NQ)*N + jo;
        for (int j = 0; j < NQ; j++) a += mid_f[g*NQ + j] * w[(size_t)j*N];
        red[t] = a;
        __syncthreads();
        if (t < 64) {
            float s = fs_b1[jo];
            #pragma unroll
            for (int q = 0; q < 8; q++) s += red[q*64 + jl];
            if (jo < 768) s_f[jo] = 1.0f + s;
            else          t_f[jo - 768] = s;
        }
    } else {
        int jo = (blk - 24)*64 + jl;
        const int N = 6144, NQ = 768;
        float a = 0.f;
        const float* w = ms_w1 + (size_t)(g*NQ)*N + jo;
        for (int j = 0; j < NQ; j++) a += mid_m[g*NQ + j] * w[(size_t)j*N];
        red[t] = a;
        __syncthreads();
        if (t < 64) {
            float s = ms_b1[jo];
            #pragma unroll
            for (int q = 0; q < 8; q++) s += red[q*64 + jl];
            if (jo < 3072) s_m[jo] = 1.0f + s;
            else           t_m[jo - 3072] = s;
        }
    }
}

// ---------------- LayerNorm: fp32 in -> bf16 out ----------------
__global__ __launch_bounds__(256) void ln_bf16_kernel(const float* __restrict__ in,
        const float* __restrict__ w, const float* __restrict__ b,
        __hip_bfloat16* __restrict__ out) {
    int row = blockIdx.x*4 + (threadIdx.x >> 6);
    int l = threadIdx.x & 63;
    const float* p = in + (size_t)row*CC;
    float v[12]; float s = 0.f, sq = 0.f;
    #pragma unroll
    for (int i = 0; i < 12; i++) { float tv = p[l + 64*i]; v[i] = tv; s += tv; sq += tv*tv; }
    #pragma unroll
    for (int m = 1; m < 64; m <<= 1) { s += __shfl_xor(s, m); sq += __shfl_xor(sq, m); }
    float mean = s * (1.0f/768.0f);
    float var  = sq * (1.0f/768.0f) - mean*mean;
    float rstd = rsqrtf(var + 1e-5f);
    __hip_bfloat16* o = out + (size_t)row*CC;
    #pragma unroll
    for (int i = 0; i < 12; i++) { int c = l + 64*i; o[c] = __float2bfloat16((v[i]-mean)*rstd*w[c] + b[c]); }
}

// ---------------- LayerNorm: bf16 in -> bf16 out ----------------
__global__ __launch_bounds__(256) void ln_bf16in_kernel(const __hip_bfloat16* __restrict__ in,
        const float* __restrict__ w, const float* __restrict__ b,
        __hip_bfloat16* __restrict__ out) {
    int row = blockIdx.x*4 + (threadIdx.x >> 6);
    int l = threadIdx.x & 63;
    const __hip_bfloat16* p = in + (size_t)row*CC;
    float v[12]; float s = 0.f, sq = 0.f;
    #pragma unroll
    for (int i = 0; i < 12; i++) { float tv = __bfloat162float(p[l + 64*i]); v[i] = tv; s += tv; sq += tv*tv; }
    #pragma unroll
    for (int m = 1; m < 64; m <<= 1) { s += __shfl_xor(s, m); sq += __shfl_xor(sq, m); }
    float mean = s * (1.0f/768.0f);
    float var  = sq * (1.0f/768.0f) - mean*mean;
    float rstd = rsqrtf(var + 1e-5f);
    __hip_bfloat16* o = out + (size_t)row*CC;
    #pragma unroll
    for (int i = 0; i < 12; i++) { int c = l + 64*i; o[c] = __float2bfloat16((v[i]-mean)*rstd*w[c] + b[c]); }
}

// ---------------- twiddle matrices ----------------
__global__ __launch_bounds__(256) void ew_kernel(__hip_bfloat16* __restrict__ Ew) {
    int idx = blockIdx.x*256 + threadIdx.x;
    if (idx >= 192*384) return;
    int r = idx / 384, w = idx - (idx/384)*384;
    int f = (r < 96) ? r : r - 96;
    const float rn = 0.05270462766947299f;  // 1/sqrt(360)
    float v = 0.f;
    if (f < FF && w < WW) {
        int p = (f * w) % 360;
        float ang = 6.283185307179586f/360.0f * (float)p;
        float s_, c_; sincosf(ang, &s_, &c_);
        v = (r < 96) ? c_*rn : -s_*rn;
    }
    Ew[idx] = __float2bfloat16(v);
}

__global__ __launch_bounds__(256) void eh_kernel(__hip_bfloat16* __restrict__ Eh) {
    int idx = blockIdx.x*256 + threadIdx.x;
    if (idx >= 4*192*384) return;
    int sp = idx / (192*384);
    int rem = idx - sp*(192*384);
    int t = rem / 384, k = rem - (rem/384)*384;
    int sig = sp >> 1, plane = sp & 1;
    float s = (sig == 0) ? -1.f : 1.f;
    int h = (k < 192) ? k : k - 192;
    const float rnh = 0.07453559924999299f;  // 1/sqrt(180)
    float v = 0.f;
    if (t < HH && h < HH) {
        int p = (t * h) % 180;
        float ang = 6.283185307179586f/180.0f * (float)p;
        float s_, c_; sincosf(ang, &s_, &c_);
        float C = c_*rnh, S = s_*rnh;
        if (plane == 0) v = (k < 192) ? C : -s*S;
        else            v = (k < 192) ? s*S : C;
    }
    Eh[idx] = __float2bfloat16(v);
}

// ---------------- bd stacked-complex weight pack ----------------
__global__ __launch_bounds__(256) void bdw_kernel(const float* __restrict__ w,
        __hip_bfloat16* __restrict__ Bt) {
    int idx = blockIdx.x*256 + threadIdx.x;   // 8*192*192 = 294912
    if (idx >= 8*192*192) return;
    int wb = idx / (192*192);
    int rem = idx - wb*(192*192);
    int n2 = rem / 192, k2 = rem - (rem/192)*192;
    int k = (k2 < 96) ? k2 : k2 - 96;
    int oc = (n2 < 96) ? n2 : n2 - 96;
    float w0 = w[((size_t)wb*96 + k)*96 + oc];
    float w1v = w[((size_t)(8 + wb)*96 + k)*96 + oc];
    float v;
    if (n2 < 96) v = (k2 < 96) ? w0 : -w1v;
    else         v = (k2 < 96) ? w1v : w0;
    Bt[idx] = __float2bfloat16(v);
}

// ---------------- MFMA transform: C[192 rows][128 c] = A[192][384] @ B[384][c], all bf16 I/O ----------------
// staging address math hoisted out of the K-loop (only kb advances)
template<int MODE>
__global__ __launch_bounds__(256) void transform_mfma(
        const __hip_bfloat16* __restrict__ Amat,
        const __hip_bfloat16* __restrict__ B0, const __hip_bfloat16* __restrict__ B1,
        __hip_bfloat16* __restrict__ O0, __hip_bfloat16* __restrict__ O1) {
    __shared__ __align__(16) unsigned short As[192*72];
    __shared__ __align__(16) unsigned short Bs[128*72];
    int nbase = blockIdx.x * 128;
    int bat = blockIdx.z;
    int tid = threadIdx.x;
    int l = tid & 63, wv = tid >> 6;
    int wm = wv & 1, wn = wv >> 1;
    int lm = l & 15, kq = l >> 4;
    const __hip_bfloat16* Ab = Amat + (MODE == 1 ? (size_t)blockIdx.y*192*384 : 0);
    const __hip_bfloat16* pa[6];
    unsigned short* dsa[6];
    #pragma unroll
    for (int it = 0; it < 6; it++) {
        int ch = it*256 + tid;
        int row = ch >> 3, co = (ch & 7) * 8;
        pa[it]  = Ab + (size_t)row*384 + co;
        dsa[it] = As + row*72 + co;
    }
    const __hip_bfloat16* pb[4];
    int  brow[4];
    unsigned short* dsb[4];
    #pragma unroll
    for (int it = 0; it < 4; it++) {
        int idx = it*256 + tid;
        int row = idx >> 4;
        int cq = (idx & 15) * 8;
        brow[it] = row;
        dsb[it] = Bs + (size_t)cq*72 + row;   // writes at dsb + (2j)*72 / (2j+1)*72
        if (MODE == 0) {
            pb[it] = B0 + (size_t)bat*WW*CC + (size_t)row*CC + nbase + cq;
        } else {
            pb[it] = nullptr;
        }
    }
    f32x4 acc[6][4] = {};
    for (int kt = 0; kt < 6; kt++) {
        int kb = kt*64;
        __syncthreads();
        #pragma unroll
        for (int it = 0; it < 6; it++) {
            u32x4 v = *(const u32x4*)(pa[it] + kb);
            *(u32x4*)(dsa[it]) = v;
        }
        #pragma unroll
        for (int it = 0; it < 4; it++) {
            int row = brow[it];
            int k = kb + row;
            unsigned int u[4] = {0u, 0u, 0u, 0u};
            if (MODE == 0) {
                if (k < WW) {
                    u32x4 v = *(const u32x4*)(pb[it] + (size_t)kb*CC);
                    u[0] = v[0]; u[1] = v[1]; u[2] = v[2]; u[3] = v[3];
                }
            } else {
                int idx = it*256 + tid;
                int cq = (idx & 15) * 8;
                if (k < 192) {
                    if (k < HH) {
                        u32x4 v = *(const u32x4*)(B0 + (size_t)k*FF*CC + (size_t)bat*CC + nbase + cq);
                        u[0] = v[0]; u[1] = v[1]; u[2] = v[2]; u[3] = v[3];
                    }
                } else {
                    int h2 = k - 192;
                    if (h2 < HH) {
                        u32x4 v = *(const u32x4*)(B1 + (size_t)h2*FF*CC + (size_t)bat*CC + nbase + cq);
                        u[0] = v[0]; u[1] = v[1]; u[2] = v[2]; u[3] = v[3];
                    }
                }
            }
            unsigned short* db = dsb[it];
            #pragma unroll
            for (int j = 0; j < 4; j++) {
                db[(2*j    )*72] = (unsigned short)(u[j] & 0xffffu);
                db[(2*j + 1)*72] = (unsigned short)(u[j] >> 16);
            }
        }
        __syncthreads();
        #pragma unroll
        for (int kk = 0; kk < 2; kk++) {
            int kg = kk*32 + kq*8;
            bf16x8 af[6], bfv[4];
            #pragma unroll
            for (int i = 0; i < 6; i++)
                af[i] = *(const bf16x8*)(As + (wm*96 + i*16 + lm)*72 + kg);
            #pragma unroll
            for (int j = 0; j < 4; j++)
                bfv[j] = *(const bf16x8*)(Bs + (wn*64 + j*16 + lm)*72 + kg);
            #pragma unroll
            for (int i = 0; i < 6; i++)
                #pragma unroll
                for (int j = 0; j < 4; j++)
                    acc[i][j] = __builtin_amdgcn_mfma_f32_16x16x32_bf16(af[i], bfv[j], acc[i][j], 0, 0, 0);
        }
    }
    int r0 = kq * 4;
    #pragma unroll
    for (int j = 0; j < 4; j++) {
        int col = nbase + wn*64 + j*16 + lm;
        #pragma unroll
        for (int i = 0; i < 6; i++) {
            #pragma unroll
            for (int r = 0; r < 4; r++) {
                int row = wm*96 + i*16 + r0 + r;
                __hip_bfloat16 hv = __float2bfloat16(acc[i][j][r]);
                if (MODE == 0) {
                    if (row < 96) {
                        if (row < FF) O0[(size_t)bat*FF*CC + (size_t)row*CC + col] = hv;
                    } else {
                        int f2 = row - 96;
                        if (f2 < FF) O1[(size_t)bat*FF*CC + (size_t)f2*CC + col] = hv;
                    }
                } else {
                    if (row < HH) {
                        __hip_bfloat16* Op = blockIdx.y ? O1 : O0;
                        Op[(size_t)row*FF*CC + (size_t)bat*CC + col] = hv;
                    }
                }
            }
        }
    }
}

// ---------------- block-diagonal complex matmul via MFMA (stacked-complex GEMM), bf16 I/O ----------------
template<int LAYER>
__global__ __launch_bounds__(384) void bd_mfma_kernel(
        const __hip_bfloat16* __restrict__ Ir, const __hip_bfloat16* __restrict__ Ii,
        const __hip_bfloat16* __restrict__ Bt,
        const float* __restrict__ bias,
        const float* __restrict__ sf, const float* __restrict__ tf,
        __hip_bfloat16* __restrict__ Or_, __hip_bfloat16* __restrict__ Oi_) {
    __shared__ __align__(16) unsigned short As[128*72];
    __shared__ __align__(16) unsigned short Bs[192*72];
    int mbase = blockIdx.x * 128;
    int wb = blockIdx.y;
    int tid = threadIdx.x;
    int l = tid & 63, wv = tid >> 6;      // 6 waves
    int wm = wv & 1, wn = wv >> 1;
    int lm = l & 15, kq = l >> 4;
    const __hip_bfloat16* Bw = Bt + (size_t)wb*192*192;
    f32x4 acc[4][4] = {};
    for (int kt = 0; kt < 3; kt++) {
        __syncthreads();
        for (int ch = tid; ch < 1024; ch += 384) {
            int row = ch >> 3, q = ch & 7;
            int k2 = kt*64 + q*8;
            int p = mbase + row; if (p >= NPOS) p = NPOS - 1;
            const __hip_bfloat16* src = (k2 < 96) ? (Ir + (size_t)p*CC + wb*96 + k2)
                                                  : (Ii + (size_t)p*CC + wb*96 + (k2 - 96));
            *(u32x4*)(As + row*72 + q*8) = *(const u32x4*)src;
        }
        for (int ch = tid; ch < 1536; ch += 384) {
            int row = ch >> 3, co = (ch & 7) * 8;
            u32x4 v = *(const u32x4*)(Bw + (size_t)row*192 + kt*64 + co);
            *(u32x4*)(Bs + row*72 + co) = v;
        }
        __syncthreads();
        #pragma unroll
        for (int kk = 0; kk < 2; kk++) {
            int kg = kk*32 + kq*8;
            bf16x8 af[4], bfv[4];
            #pragma unroll
            for (int i = 0; i < 4; i++) {
                af[i]  = *(const bf16x8*)(As + (wm*64 + i*16 + lm)*72 + kg);
                bfv[i] = *(const bf16x8*)(Bs + (wn*64 + i*16 + lm)*72 + kg);
            }
            #pragma unroll
            for (int i = 0; i < 4; i++)
                #pragma unroll
                for (int j = 0; j < 4; j++)
                    acc[i][j] = __builtin_amdgcn_mfma_f32_16x16x32_bf16(af[i], bfv[j], acc[i][j], 0, 0, 0);
        }
    }
    int r0 = kq * 4;
    #pragma unroll
    for (int j = 0; j < 4; j++) {
        int n2 = wn*64 + j*16 + lm;
        int oc = (n2 < 96) ? n2 : n2 - 96;
        float bb = bias[((n2 < 96) ? 0 : 768) + wb*96 + oc];
        float ss = 0.f, tt = 0.f;
        if (LAYER == 0) { ss = sf[wb*96 + oc]; tt = tf[wb*96 + oc]; }
        __hip_bfloat16* Op = (n2 < 96) ? Or_ : Oi_;
        #pragma unroll
        for (int i = 0; i < 4; i++) {
            #pragma unroll
            for (int r = 0; r < 4; r++) {
                int p = mbase + wm*64 + i*16 + r0 + r;
                if (p < NPOS) {
                    float v = acc[i][j][r] + bb;
                    if (LAYER == 0) {
                        v = fmaxf(v*ss + tt, 0.0f);
                    } else {
                        v = (v > 0.01f) ? (v - 0.01f) : ((v < -0.01f) ? (v + 0.01f) : 0.0f);
                    }
                    Op[(size_t)p*CC + wb*96 + oc] = __float2bfloat16(v);
                }
            }
        }
    }
}

// ---------------- inverse W-DFT matrices (bf16) ----------------
__global__ __launch_bounds__(256) void aw_kernel(__hip_bfloat16* __restrict__ Aw) {
    int idx = blockIdx.x*256 + threadIdx.x;   // 384*96 = 36864
    if (idx >= 384*96) return;
    int w = idx / 96, f = idx - (idx/96)*96;
    const float rn = 0.05270462766947299f;
    float m = (f == 0) ? rn : ((f < FF) ? 2.0f*rn : 0.0f);
    int p = (int)(((long long)f * w) % 360);
    float ang = 6.283185307179586f / 360.0f * (float)p;
    float s_, c_; sincosf(ang, &s_, &c_);
    Aw[idx]          = __float2bfloat16(m * c_);
    Aw[384*96 + idx] = __float2bfloat16(-m * s_);
}

// ---------------- inverse rDFT along W via MFMA; hbf = bf16(idft + hln + x) ----------------
__global__ __launch_bounds__(256) void iwdft_mfma_kernel(
        const __hip_bfloat16* __restrict__ Zr, const __hip_bfloat16* __restrict__ Zi,
        const __hip_bfloat16* __restrict__ Aw,
        const __hip_bfloat16* __restrict__ hlnb,
        const float* __restrict__ xin, __hip_bfloat16* __restrict__ hbf) {
    __shared__ __align__(16) unsigned short As[128*104];
    __shared__ __align__(16) unsigned short Bs[128*104];
    int h = blockIdx.z;
    int mbase = blockIdx.y * 128;   // w
    int nbase = blockIdx.x * 128;   // c
    int tid = threadIdx.x;
    int l = tid & 63, wv = tid >> 6;
    int wm = wv & 1, wn = wv >> 1;
    int lm = l & 15, kq = l >> 4;
    f32x4 acc[4][4] = {};
    #pragma unroll
    for (int ph = 0; ph < 2; ph++) {
        __syncthreads();
        for (int ch = tid; ch < 1536; ch += 256) {
            int row = ch / 12, co = (ch - row*12) * 8;
            u32x4 v = *(const u32x4*)(Aw + ((size_t)ph*384 + mbase + row)*96 + co);
            *(u32x4*)(As + row*104 + co) = v;
        }
        const __hip_bfloat16* Zp = ph ? Zi : Zr;
        for (int ch = tid; ch < 1536; ch += 256) {   // 96 f x 16 groups of 8 c
            int f = ch >> 4, cq = (ch & 15) * 8;
            unsigned int u[4] = {0u, 0u, 0u, 0u};
            if (f < FF) {
                u32x4 v = *(const u32x4*)(Zp + ((size_t)h*FF + f)*CC + nbase + cq);
                u[0] = v[0]; u[1] = v[1]; u[2] = v[2]; u[3] = v[3];
            }
            #pragma unroll
            for (int j = 0; j < 4; j++) {
                Bs[(cq + 2*j    )*104 + f] = (unsigned short)(u[j] & 0xffffu);
                Bs[(cq + 2*j + 1)*104 + f] = (unsigned short)(u[j] >> 16);
            }
        }
        __syncthreads();
        #pragma unroll
        for (int ks = 0; ks < 3; ks++) {
            int kg = ks*32 + kq*8;
            bf16x8 af[4], bfv[4];
            #pragma unroll
            for (int i = 0; i < 4; i++) {
                af[i]  = *(const bf16x8*)(As + (wm*64 + i*16 + lm)*104 + kg);
                bfv[i] = *(const bf16x8*)(Bs + (wn*64 + i*16 + lm)*104 + kg);
            }
            #pragma unroll
            for (int i = 0; i < 4; i++)
                #pragma unroll
                for (int j = 0; j < 4; j++)
                    acc[i][j] = __builtin_amdgcn_mfma_f32_16x16x32_bf16(af[i], bfv[j], acc[i][j], 0, 0, 0);
        }
    }
    int r0 = kq * 4;
    #pragma unroll
    for (int j = 0; j < 4; j++) {
        int col = nbase + wn*64 + j*16 + lm;
        #pragma unroll
        for (int i = 0; i < 4; i++) {
            int rowb = wm*64 + i*16 + r0;
            #pragma unroll
            for (int r = 0; r < 4; r++) {
                int wp = mbase + rowb + r;
                if (wp < WW) {
                    size_t idx = ((size_t)h*WW + wp)*CC + col;
                    float v = acc[i][j][r] + __bfloat162float(hlnb[idx]) + xin[idx];
                    hbf[idx] = __float2bfloat16(v);
                }
            }
        }
    }
}

// ---------------- tiled weight transpose + bf16 convert ----------------
__global__ __launch_bounds__(256) void transpose_bf16_kernel(const float* __restrict__ src,
        __hip_bfloat16* __restrict__ dst, int K, int N) {
    __shared__ float tile[32][33];
    int n0 = blockIdx.x * 32;
    int k0 = blockIdx.y * 32;
    int tx = threadIdx.x & 31;
    int ty = threadIdx.x >> 5;
    #pragma unroll
    for (int r = 0; r < 32; r += 8) {
        tile[ty + r][tx] = src[(size_t)(k0 + ty + r) * N + n0 + tx];
    }
    __syncthreads();
    #pragma unroll
    for (int r = 0; r < 32; r += 8) {
        dst[(size_t)(n0 + ty + r) * K + k0 + tx] = __float2bfloat16(tile[tx][ty + r]);
    }
}

// ---------------- bf16 MFMA GEMM, 256x256 tile, BK=64, 8 waves (2M x 4N), 2-phase dbuf ----------------
// 1D grid + bijective XCD-chunked swizzle (T1/m204); XOR-swizzle slot = kchunk ^ (row&7)
// staging address math hoisted out of the K-loop
// MODE 0: out = bf16(gelu((A@B + bias)*s + t)), LDS-staged coalesced store
// MODE 1: out(fp32) = A@B + bias + bf16_resid
template<int MODE>
__global__ __launch_bounds__(512, 2) void gemm256_kernel(
        const __hip_bfloat16* __restrict__ A,
        const __hip_bfloat16* __restrict__ Bt,
        int M, int K, int N,
        const float* __restrict__ bias,
        const float* __restrict__ sv, const float* __restrict__ tv,
        const void* resid, void* out) {
    __shared__ __align__(16) unsigned short SH[65536];    // 128 KB
    unsigned short* Asb = SH;            // [2][256*64]
    unsigned short* Bsb = SH + 32768;    // [2][256*64]
    int tid = threadIdx.x;
    // bijective XCD swizzle (m204)
    int nwg = gridDim.x;
    int q8 = nwg >> 3, r8 = nwg & 7;
    int bid = blockIdx.x;
    int xcd = bid & 7;
    int lid = ((xcd < r8) ? xcd*(q8 + 1) : r8*(q8 + 1) + (xcd - r8)*q8) + (bid >> 3);
    int nx = N >> 8;
    int by = lid / nx;
    int bx = lid - by*nx;
    int nbase = bx << 8;
    int mbase = by << 8;
    int l = tid & 63, wv = tid >> 6;     // 8 waves
    int wm = wv & 1, wn = wv >> 1;       // wm 0..1 (128 rows), wn 0..3 (64 cols)
    int lm = l & 15, kq = l >> 4;
    f32x4 acc[8][4] = {};
    int nkt = K >> 6;

    const __hip_bfloat16* pga[4];
    const __hip_bfloat16* pgb[4];
    int ldso[4];
    #pragma unroll
    for (int i = 0; i < 4; i++) {
        int ch = i*512 + tid;            // 0..2047
        int row = ch >> 3;
        int sl = ch & 7;
        int kg = (sl ^ (row & 7)) << 3;
        int am = mbase + row; if (am >= M) am = M - 1;
        pga[i] = A  + (size_t)am * K + kg;
        pgb[i] = Bt + (size_t)(nbase + row) * K + kg;
        ldso[i] = ch*8;
    }
    auto stage = [&](int d, int kt) {
        int kb = kt << 6;
        int db = d*16384;
        #pragma unroll
        for (int i = 0; i < 4; i++) {
            __builtin_amdgcn_global_load_lds(
                (const __attribute__((address_space(1))) void*)(unsigned long long)(uintptr_t)(pga[i] + kb),
                (__attribute__((address_space(3))) void*)(unsigned long long)(uintptr_t)(Asb + db + ldso[i]),
                16, 0, 0);
            __builtin_amdgcn_global_load_lds(
                (const __attribute__((address_space(1))) void*)(unsigned long long)(uintptr_t)(pgb[i] + kb),
                (__attribute__((address_space(3))) void*)(unsigned long long)(uintptr_t)(Bsb + db + ldso[i]),
                16, 0, 0);
        }
    };

    stage(0, 0);
    __syncthreads();
    for (int kt = 0; kt < nkt; kt++) {
        if (kt + 1 < nkt) stage((kt + 1) & 1, kt + 1);   // prefetch next K-tile
        int d = kt & 1;
        const unsigned short* Ab = Asb + d*16384;
        const unsigned short* Bb = Bsb + d*16384;
        #pragma unroll
        for (int kk = 0; kk < 2; kk++) {
            bf16x8 af[8], bfv[4];
            #pragma unroll
            for (int i = 0; i < 8; i++) {
                int ra = wm*128 + i*16 + lm;
                af[i] = *(const bf16x8*)(Ab + ra*64 + ((((kk<<2)+kq) ^ (ra&7))<<3));
            }
            #pragma unroll
            for (int j = 0; j < 4; j++) {
                int rb = wn*64 + j*16 + lm;
                bfv[j] = *(const bf16x8*)(Bb + rb*64 + ((((kk<<2)+kq) ^ (rb&7))<<3));
            }
            #pragma unroll
            for (int i = 0; i < 8; i++)
                #pragma unroll
                for (int j = 0; j < 4; j++)
                    acc[i][j] = __builtin_amdgcn_mfma_f32_16x16x32_bf16(af[i], bfv[j], acc[i][j], 0, 0, 0);
        }
        __syncthreads();
    }

    int r0 = kq * 4;
    if (MODE == 0) {
        // epilogue: gelu+mod -> bf16 tile in LDS [256][256], then coalesced store
        #pragma unroll
        for (int j = 0; j < 4; j++) {
            int col = wn*64 + j*16 + lm;
            int gcol = nbase + col;
            float bb = bias[gcol];
            float ss = sv[gcol], tt = tv[gcol];
            #pragma unroll
            for (int i = 0; i < 8; i++) {
                int rowb = wm*128 + i*16 + r0;
                #pragma unroll
                for (int r = 0; r < 4; r++) {
                    float v = gelu_f((acc[i][j][r] + bb)*ss + tt);
                    __hip_bfloat16 hb = __float2bfloat16(v);
                    SH[(rowb + r)*256 + col] = *reinterpret_cast<unsigned short*>(&hb);
                }
            }
        }
        __syncthreads();
        #pragma unroll
        for (int it = 0; it < 16; it++) {
            int chunk = it*512 + tid;    // 8192 chunks of 16B (256 rows x 32)
            int row = chunk >> 5;
            int c8 = chunk & 31;
            int mr = mbase + row;
            if (mr < M) {
                *(u32x4*)((__hip_bfloat16*)out + (size_t)mr*N + nbase + c8*8) =
                    *(const u32x4*)(SH + row*256 + c8*8);
            }
        }
    } else {
        const __hip_bfloat16* rb16 = (const __hip_bfloat16*)resid;
        #pragma unroll
        for (int j = 0; j < 4; j++) {
            int col = nbase + wn*64 + j*16 + lm;
            float bb = bias[col];
            #pragma unroll
            for (int i = 0; i < 8; i++) {
                int rowb = mbase + wm*128 + i*16 + r0;
                #pragma unroll
                for (int r = 0; r < 4; r++) {
                    int row = rowb + r;
                    if (row < M) {
                        float v = acc[i][j][r] + bb;
                        ((float*)out)[(size_t)row*N + col] =
                            v + __bfloat162float(rb16[(size_t)row*N + col]);
                    }
                }
            }
        }
    }
}

extern "C" void kernel_launch(void* const* d_in, const int* in_sizes, int n_in,
                              void* d_out, int out_size, void* d_ws, size_t ws_size,
                              hipStream_t stream) {
    const float* x     = (const float*)d_in[0];
    const float* emb   = (const float*)d_in[1];
    const float* n1w   = (const float*)d_in[2];
    const float* n1b   = (const float*)d_in[3];
    const float* n2w   = (const float*)d_in[4];
    const float* n2b   = (const float*)d_in[5];
    const float* w1    = (const float*)d_in[6];
    const float* b1    = (const float*)d_in[7];
    const float* w2    = (const float*)d_in[8];
    const float* b2    = (const float*)d_in[9];
    const float* fs_w0 = (const float*)d_in[10];
    const float* fs_b0 = (const float*)d_in[11];
    const float* fs_w1 = (const float*)d_in[12];
    const float* fs_b1 = (const float*)d_in[13];
    const float* fc1w  = (const float*)d_in[14];
    const float* fc1b  = (const float*)d_in[15];
    const float* fc2w  = (const float*)d_in[16];
    const float* fc2b  = (const float*)d_in[17];
    const float* ms_w0 = (const float*)d_in[18];
    const float* ms_b0 = (const float*)d_in[19];
    const float* ms_w1 = (const float*)d_in[20];
    const float* ms_b1 = (const float*)d_in[21];
    float* out = (float*)d_out;
    (void)in_sizes; (void)n_in; (void)out_size; (void)ws_size;

    char* wsb = (char*)d_ws;
    size_t off = 0;
    auto alloc = [&](size_t nbytes) -> void* {
        void* p = wsb + off;
        off += (nbytes + 255) & ~(size_t)255;
        return p;
    };
    float* s_f  = (float*)alloc(768*4);
    float* t_f  = (float*)alloc(768*4);
    float* s_m  = (float*)alloc(3072*4);
    float* t_m  = (float*)alloc(3072*4);
    float* midf = (float*)alloc(1536*4);
    float* midm = (float*)alloc(6144*4);
    __hip_bfloat16* Aw  = (__hip_bfloat16*)alloc((size_t)2*384*96*2);
    __hip_bfloat16* Ew  = (__hip_bfloat16*)alloc((size_t)192*384*2);
    __hip_bfloat16* Eh  = (__hip_bfloat16*)alloc((size_t)4*192*384*2);
    __hip_bfloat16* Bt1 = (__hip_bfloat16*)alloc((size_t)8*192*192*2);
    __hip_bfloat16* Bt2 = (__hip_bfloat16*)alloc((size_t)8*192*192*2);
    __hip_bfloat16* Yrb = (__hip_bfloat16*)alloc((size_t)NPOS*CC*2);
    __hip_bfloat16* Yib = (__hip_bfloat16*)alloc((size_t)NPOS*CC*2);
    __hip_bfloat16* Zrb = (__hip_bfloat16*)alloc((size_t)NPOS*CC*2);
    __hip_bfloat16* Zib = (__hip_bfloat16*)alloc((size_t)NPOS*CC*2);
    __hip_bfloat16* wT1  = (__hip_bfloat16*)alloc((size_t)CC*LAT*2);
    __hip_bfloat16* wT2  = (__hip_bfloat16*)alloc((size_t)CC*LAT*2);
    __hip_bfloat16* h2   = (__hip_bfloat16*)alloc((size_t)NROW*CC*2);
    __hip_bfloat16* hbf  = (__hip_bfloat16*)alloc((size_t)NROW*CC*2);
    __hip_bfloat16* hmid = (__hip_bfloat16*)alloc((size_t)NROW*LAT*2);
    // h_ln (bf16) aliases h2: lifetimes are disjoint
    __hip_bfloat16* hlnb = h2;

    // 1. modulation scale/shift vectors + twiddle/weight matrices
    mod_a_kernel<<<30, 256, 0, stream>>>(emb, fs_w0, fs_b0, ms_w0, ms_b0, midf, midm);
    mod_b_kernel<<<120, 512, 0, stream>>>(midf, midm, fs_w1, fs_b1, ms_w1, ms_b1,
                                          s_f, t_f, s_m, t_m);
    aw_kernel<<<144, 256, 0, stream>>>(Aw);
    ew_kernel<<<288, 256, 0, stream>>>(Ew);
    eh_kernel<<<1152, 256, 0, stream>>>(Eh);
    bdw_kernel<<<1152, 256, 0, stream>>>(w1, Bt1);
    bdw_kernel<<<1152, 256, 0, stream>>>(w2, Bt2);
    // 2. LN1 -> hlnb (bf16)
    ln_bf16_kernel<<<NROW/4, 256, 0, stream>>>(x, n1w, n1b, hlnb);
    // 3. weight convert+transpose
    transpose_bf16_kernel<<<dim3(LAT/32, CC/32), 256, 0, stream>>>(fc1w, wT1, 768, 3072);
    transpose_bf16_kernel<<<dim3(CC/32, LAT/32), 256, 0, stream>>>(fc2w, wT2, 3072, 768);

    // 4. filter path, all MFMA, bf16 intermediates
    transform_mfma<0><<<dim3(6, 1, 180), 256, 0, stream>>>(Ew, hlnb, nullptr, Yrb, Yib);
    transform_mfma<1><<<dim3(6, 2, 91), 256, 0, stream>>>(Eh, Yrb, Yib, Zrb, Zib);               // fwd
    bd_mfma_kernel<0><<<dim3(128, 8), 384, 0, stream>>>(Zrb, Zib, Bt1, b1, s_f, t_f, Yrb, Yib);
    bd_mfma_kernel<1><<<dim3(128, 8), 384, 0, stream>>>(Yrb, Yib, Bt2, b2, nullptr, nullptr, Zrb, Zib);
    transform_mfma<1><<<dim3(6, 2, 91), 256, 0, stream>>>(Eh + (size_t)2*192*384, Zrb, Zib, Yrb, Yib);  // inv
    // hbf = bf16(idft + hln + x)   (the residual stream h, bf16)
    iwdft_mfma_kernel<<<dim3(6, 3, 180), 256, 0, stream>>>(Yrb, Yib, Aw, hlnb, x, hbf);

    // 5. MLP path: LN2(hbf) -> fc1 -> fc2 + hbf -> d_out (fp32, full coverage)
    ln_bf16in_kernel<<<NROW/4, 256, 0, stream>>>(hbf, n2w, n2b, h2);
    gemm256_kernel<0><<<dim3((LAT/256) * ((NROW+255)/256)), 512, 0, stream>>>(
        h2, wT1, NROW, CC, LAT, fc1b, s_m, t_m, nullptr, hmid);
    gemm256_kernel<1><<<dim3((CC/256) * ((NROW+255)/256)), 512, 0, stream>>>(
        hmid, wT2, NROW, LAT, CC, fc2b, nullptr, nullptr, hbf, out);
}